// Round 14
// baseline (1656.283 us; speedup 1.0000x reference)
//
#include <hip/hip_runtime.h>
#include <math.h>

#define NN 2000
#define T1C 12
#define BBC 2
#define HHC 128
#define NHD 4
#define DFD 32
#define LLC 4
#define DEC 16
#define TEC 16
#define CINC 12
#define E0C 32000
#define EEC 34000
#define BTC 24
#define MROWS 48000
#define EPSLN 1e-5f
#define SCALEQK 0.17677669529663687f

typedef __attribute__((ext_vector_type(8))) short short8;
typedef __attribute__((ext_vector_type(4))) float f32x4;

// ---------------- helpers ----------------

__device__ __forceinline__ unsigned short f2b(float f)
{
    unsigned u = __float_as_uint(f);
    return (unsigned short)((u + 0x7FFF + ((u >> 16) & 1)) >> 16);
}

__device__ __forceinline__ float b2f(unsigned short h)
{
    return __uint_as_float(((unsigned)h) << 16);
}

__device__ __forceinline__ float blockSum128(float v, volatile float* s2)
{
    for (int m = 32; m >= 1; m >>= 1) v += __shfl_xor(v, m, 64);
    int w = threadIdx.x >> 6;
    __syncthreads();
    if ((threadIdx.x & 63) == 0) s2[w] = v;
    __syncthreads();
    return s2[0] + s2[1];
}

// ---------------- weight conversions ----------------

__global__ __launch_bounds__(256) void convw_k(const float* __restrict__ W, unsigned short* __restrict__ WT,
                                               int LN_, int K, int N, int Kp, int ostride, int ooff)
{
    int idx = blockIdx.x * blockDim.x + threadIdx.x;
    int total = LN_ * N * Kp;
    if (idx >= total) return;
    int l = idx / (N * Kp);
    int r = idx - l * (N * Kp);
    int n = r / Kp;
    int k = r - n * Kp;
    WT[(size_t)l * ostride + (size_t)(ooff + n) * Kp + k] =
        (k < K) ? f2b(W[(size_t)l * K * N + (size_t)k * N + n]) : 0;
}

__global__ __launch_bounds__(256) void convwp_k(const float* __restrict__ W, unsigned short* __restrict__ Bp,
                                                int LN_, int K, int N, int noff, int Ntot)
{
    int idx = blockIdx.x * blockDim.x + threadIdx.x;
    int total = LN_ * K * N;
    if (idx >= total) return;
    int l = idx / (K * N);
    int r = idx - l * (K * N);
    int k = r / N;
    int n = r - k * N + noff;
    size_t off = (size_t)l * K * Ntot +
                 ((size_t)((n >> 4) * (K >> 5) + (k >> 5)) << 9) +
                 (((k >> 3) & 3) << 7) + ((n & 15) << 3) + (k & 7);
    Bp[off] = f2b(W[idx]);
}

// ---------------- gemm2: 128x128-tile LDS-staged MFMA GEMM ----------------

template<int K, int EPI, int OUTM>
__global__ __launch_bounds__(256) void gemm2_k(
    const unsigned short* __restrict__ A, const unsigned short* __restrict__ Bp,
    const float* __restrict__ bias, float* __restrict__ C, unsigned short* __restrict__ Cb,
    const float* __restrict__ res, const float* __restrict__ gam, const float* __restrict__ bet,
    int M, int Ntot)
{
    __shared__ unsigned short A_s[128 * 16 * 8];
    __shared__ float red2[2][128][2];

    int tid = threadIdx.x;
    int w = tid >> 6, lane = tid & 63;
    int wr = w & 1, wc = w >> 1;
    int quad = lane >> 4, lr = lane & 15;

    const unsigned short* abase = A + (size_t)blockIdx.x * 128 * K;
    int ntg0 = blockIdx.y * 8 + wc * 4;

    f32x4 acc[4][4];
#pragma unroll
    for (int mt = 0; mt < 4; mt++)
#pragma unroll
        for (int nt = 0; nt < 4; nt++) acc[mt][nt] = (f32x4){0.f, 0.f, 0.f, 0.f};

#pragma unroll
    for (int kb = 0; kb < K; kb += 128) {
        if (kb) __syncthreads();
#pragma unroll
        for (int j = 0; j < 8; j++) {
            int s = j * 256 + tid;
            int row = s >> 4, ks = s & 15;
            int ko = ks ^ (row & 15);
            uint4 d = *(const uint4*)(abase + (size_t)row * K + kb + ko * 8);
            *(uint4*)(A_s + s * 8) = d;
        }
        __syncthreads();
#pragma unroll
        for (int k0 = 0; k0 < 128; k0 += 32) {
            short8 af[4], bf[4];
#pragma unroll
            for (int mt = 0; mt < 4; mt++) {
                int row_l = wr * 64 + mt * 16 + lr;
                int koct = (k0 >> 3) + quad;
                int slot = row_l * 16 + (koct ^ lr);
                af[mt] = *(const short8*)(A_s + slot * 8);
            }
#pragma unroll
            for (int nt = 0; nt < 4; nt++) {
                size_t off = ((size_t)(ntg0 + nt) * (K >> 5) + ((kb + k0) >> 5)) * 512 + lane * 8;
                bf[nt] = *(const short8*)(Bp + off);
            }
#pragma unroll
            for (int mt = 0; mt < 4; mt++)
#pragma unroll
                for (int nt = 0; nt < 4; nt++)
                    acc[mt][nt] = __builtin_amdgcn_mfma_f32_16x16x32_bf16(af[mt], bf[nt], acc[mt][nt], 0, 0, 0);
        }
    }

    int rbase = blockIdx.x * 128 + wr * 64;
    int cbase = blockIdx.y * 128 + wc * 64;

    if constexpr (EPI != 3) {
#pragma unroll
        for (int mt = 0; mt < 4; mt++) {
#pragma unroll
            for (int nt = 0; nt < 4; nt++) {
                int colg = cbase + nt * 16 + lr;
                float bv = bias ? bias[colg] : 0.f;
#pragma unroll
                for (int i = 0; i < 4; i++) {
                    int row = rbase + mt * 16 + quad * 4 + i;
                    float x = acc[mt][nt][i] + bv;
                    if constexpr (EPI == 1) x = 0.5f * x * (1.f + erff(x * 0.70710678118654752f));
                    if constexpr (EPI == 2) x = res[(size_t)row * Ntot + colg] + x;
                    if constexpr (OUTM & 1) C[(size_t)row * Ntot + colg] = x;
                    if constexpr (OUTM & 4)
                        Cb[(size_t)blockIdx.y * M * 128 + (size_t)row * 128 + (wc * 64 + nt * 16 + lr)] = f2b(x);
                    else if constexpr (OUTM & 2)
                        Cb[(size_t)row * Ntot + colg] = f2b(x);
                }
            }
        }
    } else {
        float s[4][4], s2l[4][4];
#pragma unroll
        for (int mt = 0; mt < 4; mt++)
#pragma unroll
            for (int i = 0; i < 4; i++) { s[mt][i] = 0.f; s2l[mt][i] = 0.f; }
#pragma unroll
        for (int mt = 0; mt < 4; mt++) {
#pragma unroll
            for (int nt = 0; nt < 4; nt++) {
                int colg = cbase + nt * 16 + lr;
                float bv = bias[colg];
#pragma unroll
                for (int i = 0; i < 4; i++) {
                    int row = rbase + mt * 16 + quad * 4 + i;
                    float x = acc[mt][nt][i] + bv + res[(size_t)row * 128 + colg];
                    acc[mt][nt][i] = x;
                    s[mt][i] += x;
                    s2l[mt][i] += x * x;
                }
            }
        }
#pragma unroll
        for (int m = 1; m < 16; m <<= 1) {
#pragma unroll
            for (int mt = 0; mt < 4; mt++)
#pragma unroll
                for (int i = 0; i < 4; i++) {
                    s[mt][i]  += __shfl_xor(s[mt][i], m, 64);
                    s2l[mt][i] += __shfl_xor(s2l[mt][i], m, 64);
                }
        }
        if (lr == 0) {
#pragma unroll
            for (int mt = 0; mt < 4; mt++)
#pragma unroll
                for (int i = 0; i < 4; i++) {
                    int rl = wr * 64 + mt * 16 + quad * 4 + i;
                    red2[wc][rl][0] = s[mt][i];
                    red2[wc][rl][1] = s2l[mt][i];
                }
        }
        __syncthreads();
#pragma unroll
        for (int mt = 0; mt < 4; mt++) {
#pragma unroll
            for (int i = 0; i < 4; i++) {
                int rl = wr * 64 + mt * 16 + quad * 4 + i;
                float st  = red2[0][rl][0] + red2[1][rl][0];
                float s2t = red2[0][rl][1] + red2[1][rl][1];
                float mu = st * (1.f / 128.f);
                float rstd = rsqrtf(s2t * (1.f / 128.f) - mu * mu + EPSLN);
                int row = rbase + mt * 16 + quad * 4 + i;
#pragma unroll
                for (int nt = 0; nt < 4; nt++) {
                    int colg = cbase + nt * 16 + lr;
                    float y = (acc[mt][nt][i] - mu) * rstd * gam[colg] + bet[colg];
                    if constexpr (OUTM & 1) C[(size_t)row * 128 + colg] = y;
                    if constexpr (OUTM & 2) Cb[(size_t)row * 128 + colg] = f2b(y);
                }
            }
        }
    }
}

template<int K, int EPI, int OUTM>
static void run_gemm2(const unsigned short* A, const unsigned short* Bp, const float* bias,
                      float* C, unsigned short* Cb, const float* res, const float* g, const float* be,
                      int M, int Ntot, hipStream_t stream)
{
    dim3 grid(M / 128, Ntot / 128);
    gemm2_k<K, EPI, OUTM><<<grid, 256, 0, stream>>>(A, Bp, bias, C, Cb, res, g, be, M, Ntot);
}

// ---------------- old-style MFMA GEMM (e1: K=288, N=64, M=34000) ----------------

template<int NT, int EPI, int OUTM>
__global__ __launch_bounds__(256) void gemm_mfma_k(
    const unsigned short* __restrict__ A, const unsigned short* __restrict__ WT,
    const float* __restrict__ bias, float* __restrict__ C, unsigned short* __restrict__ Cb,
    const float* __restrict__ res, const float* __restrict__ gam, const float* __restrict__ bet,
    int M, int K)
{
    const int Nc = NT * 32;
    int tid = threadIdx.x;
    int w = tid >> 6, lane = tid & 63;
    int wr = w & 1, wc = w >> 1;
    int r0 = blockIdx.x * 32 + wr * 16;
    int c0 = wc * NT * 16;
    int lr = lane & 15;
    int kq = (lane >> 4) * 8;
    int arow = r0 + lr; if (arow >= M) arow = M - 1;
    const unsigned short* ap = A + (size_t)arow * K + kq;
    const unsigned short* wp = WT + (size_t)(c0 + lr) * K + kq;

    f32x4 acc[NT];
#pragma unroll
    for (int t = 0; t < NT; t++) acc[t] = (f32x4){0.f, 0.f, 0.f, 0.f};

    for (int k0 = 0; k0 < K; k0 += 32) {
        short8 a = *(const short8*)(ap + k0);
#pragma unroll
        for (int t = 0; t < NT; t++) {
            short8 b = *(const short8*)(wp + (size_t)t * 16 * K + k0);
            acc[t] = __builtin_amdgcn_mfma_f32_16x16x32_bf16(a, b, acc[t], 0, 0, 0);
        }
    }

    int orow0 = r0 + (lane >> 4) * 4;
#pragma unroll
    for (int t = 0; t < NT; t++) {
        int col = c0 + t * 16 + lr;
        float bv = bias ? bias[col] : 0.f;
#pragma unroll
        for (int i = 0; i < 4; i++) {
            int row = orow0 + i;
            if (row < M) {
                float x = acc[t][i] + bv;
                if constexpr (EPI == 1) x = 0.5f * x * (1.f + erff(x * 0.70710678118654752f));
                if constexpr (EPI == 2) x = res[(size_t)row * Nc + col] + x;
                if constexpr (OUTM & 1) C[(size_t)row * Nc + col] = x;
                if constexpr (OUTM & 2) Cb[(size_t)row * Nc + col] = f2b(x);
            }
        }
    }
}

// ---------------- fp32 fallback GEMM (small: e2) ----------------

template<int EPI, int K>
__global__ __launch_bounds__(128) void gemm_k(
    const float* __restrict__ A, const float* __restrict__ W,
    const float* __restrict__ bias, float* __restrict__ C,
    int M, int Nc)
{
    __shared__ float As[16 * K];
    int tid = threadIdx.x;
    int row0 = blockIdx.x * 16;
    for (int i = tid; i < 16 * K; i += 128) {
        int r = i / K, k = i - r * K;
        int row = row0 + r;
        As[i] = (row < M) ? A[(size_t)row * K + k] : 0.f;
    }
    __syncthreads();
    for (int c = tid; c < Nc; c += 128) {
        float acc[16];
#pragma unroll
        for (int r = 0; r < 16; r++) acc[r] = 0.f;
        const float* wp = W + c;
        for (int k = 0; k < K; k++) {
            float w = wp[(size_t)k * Nc];
#pragma unroll
            for (int r = 0; r < 16; r++) acc[r] += As[r * K + k] * w;
        }
        float bv = bias ? bias[c] : 0.f;
#pragma unroll
        for (int r = 0; r < 16; r++) {
            int row = row0 + r;
            if (row < M) C[(size_t)row * Nc + c] = acc[r] + bv;
        }
    }
}

// ---------------- graph precompute ----------------

__global__ __launch_bounds__(256) void zero_deg_k(int* __restrict__ degi)
{
    int i = blockIdx.x * blockDim.x + threadIdx.x;
    if (i < NN) degi[i] = 0;
}

__global__ __launch_bounds__(256) void build_edges_k(const int* __restrict__ eidx,
                                                     int* __restrict__ dst, int* __restrict__ src,
                                                     int* __restrict__ degi)
{
    int e = blockIdx.x * blockDim.x + threadIdx.x;
    if (e >= EEC) return;
    int d, s;
    if (e < E0C) { d = eidx[e]; s = eidx[E0C + e]; }
    else { d = e - E0C; s = e - E0C; }
    dst[e] = d;
    src[e] = s;
    atomicAdd(&degi[d], 1);
}

__global__ __launch_bounds__(256) void scan_k(const int* __restrict__ degi, int* __restrict__ rowptr,
                                              int* __restrict__ cursor, float* __restrict__ degmaxf)
{
    __shared__ int ssum[256];
    __shared__ int smx[256];
    int tid = threadIdx.x;
    int vals[8];
    int s = 0, mx = 0;
    int base = tid * 8;
#pragma unroll
    for (int j = 0; j < 8; j++) {
        int idx = base + j;
        int v = (idx < NN) ? degi[idx] : 0;
        vals[j] = v; s += v; mx = max(mx, v);
    }
    ssum[tid] = s; smx[tid] = mx;
    __syncthreads();
    for (int off = 1; off < 256; off <<= 1) {
        int t = (tid >= off) ? ssum[tid - off] : 0;
        __syncthreads();
        ssum[tid] += t;
        __syncthreads();
    }
    for (int off = 128; off > 0; off >>= 1) {
        if (tid < off) smx[tid] = max(smx[tid], smx[tid + off]);
        __syncthreads();
    }
    if (tid == 0) *degmaxf = fmaxf((float)smx[0], 1.f);
    int running = ssum[tid] - s;
#pragma unroll
    for (int j = 0; j < 8; j++) {
        int idx = base + j;
        if (idx < NN) { rowptr[idx] = running; cursor[idx] = running; running += vals[j]; }
    }
    if (tid == 255) rowptr[NN] = ssum[255];
}

__global__ __launch_bounds__(256) void feat_k(const int* __restrict__ dst, const int* __restrict__ src,
                                              const int* __restrict__ degi, const float* __restrict__ degmaxf,
                                              int* __restrict__ cursor, int* __restrict__ srcCSR,
                                              int* __restrict__ dstCSR, int* __restrict__ epos,
                                              const float* __restrict__ We, const float* __restrict__ bE,
                                              float* __restrict__ e)
{
    int ei = blockIdx.x * blockDim.x + threadIdx.x;
    if (ei >= EEC) return;
    int d = dst[ei], s = src[ei];
    int pos = atomicAdd(&cursor[d], 1);
    srcCSR[pos] = s;
    dstCSR[pos] = d;
    epos[ei] = pos;
    float dm = *degmaxf;
    float degd = (float)degi[d], degs = (float)degi[s];
    float f0 = 1.f / fmaxf(degd, 1.f);
    float f1 = degs / dm, f2 = degd / dm;
#pragma unroll
    for (int c = 0; c < DEC; c++)
        e[ei * DEC + c] = bE[c] + f0 * We[c] + f1 * We[DEC + c] + f2 * We[2 * DEC + c];
}

// ---------------- embedding ----------------

__global__ __launch_bounds__(128) void embed_k(const float* __restrict__ Xk, const float* __restrict__ temb,
                                               const float* __restrict__ Win, const float* __restrict__ bin,
                                               const float* __restrict__ g, const float* __restrict__ be,
                                               const float* __restrict__ stepemb, const int* __restrict__ kidx,
                                               float* __restrict__ h, unsigned short* __restrict__ hb)
{
    int row = blockIdx.x;
    int t = row % T1C;
    int bn = row / T1C;
    int b = bn / NN;
    __shared__ float x[28];
    __shared__ float s2[2];
    int tid = threadIdx.x;
    if (tid < CINC) x[tid] = Xk[(size_t)row * CINC + tid];
    else if (tid < 28) x[tid] = temb[t * TEC + (tid - CINC)];
    __syncthreads();
    float acc = bin[tid];
#pragma unroll
    for (int k = 0; k < 28; k++) acc += x[k] * Win[k * HHC + tid];
    float m = blockSum128(acc, s2) * (1.f / 128.f);
    float d = acc - m;
    float v = blockSum128(d * d, s2) * (1.f / 128.f);
    float val = d * rsqrtf(v + EPSLN) * g[tid] + be[tid] + stepemb[(size_t)kidx[b] * HHC + tid];
    h[(size_t)row * HHC + tid] = val;
    hb[(size_t)row * HHC + tid] = f2b(val);
}

__global__ __launch_bounds__(128) void tre_k(const float* __restrict__ temb, const float* __restrict__ Wtr,
                                             const float* __restrict__ btr, float* __restrict__ tre)
{
    int t = blockIdx.x, c = threadIdx.x;
    float acc = btr[c];
#pragma unroll
    for (int k = 0; k < TEC; k++) acc += temb[t * TEC + k] * Wtr[k * HHC + c];
    tre[t * HHC + c] = acc;
}

// ---------------- temporal attention (vectorized bf16 staging) ----------------

__global__ __launch_bounds__(128) void temporal_attn_k(const unsigned short* __restrict__ qkvb,
                                                       unsigned short* __restrict__ outb)
{
    int bn = blockIdx.x;
    __shared__ float q[T1C][132], k[T1C][132], v[T1C][132];
    __shared__ float s[NHD][T1C][T1C];
    int tid = threadIdx.x;
    int hh = tid >> 5, lane = tid & 31;
    const unsigned short* base = qkvb + (size_t)bn * T1C * 384;
    // 576 uint4 chunks of 8 bf16 each; chunk never straddles q/k/v (128,256 are mult of 8)
    for (int sIdx = tid; sIdx < 576; sIdx += 128) {
        uint4 d = *(const uint4*)(base + sIdx * 8);
        int t = sIdx / 48;
        int c0 = (sIdx - t * 48) * 8;
        float f[8];
        unsigned u[4] = {d.x, d.y, d.z, d.w};
#pragma unroll
        for (int j = 0; j < 4; j++) {
            f[2 * j]     = __uint_as_float(u[j] << 16);
            f[2 * j + 1] = __uint_as_float(u[j] & 0xFFFF0000u);
        }
        float* dstp;
        if (c0 < 128) dstp = &q[t][c0];
        else if (c0 < 256) dstp = &k[t][c0 - 128];
        else dstp = &v[t][c0 - 256];
#pragma unroll
        for (int j = 0; j < 8; j++) dstp[j] = f[j];
    }
    __syncthreads();
    for (int idx = lane; idx < T1C * T1C; idx += 32) {
        int tq = idx / T1C, tk = idx - tq * T1C;
        float acc = 0.f;
        int off = hh * 32;
#pragma unroll
        for (int d = 0; d < 32; d++) acc += q[tq][off + d] * k[tk][off + d];
        s[hh][tq][tk] = acc * SCALEQK;
    }
    __syncthreads();
    if (tid < NHD * T1C) {
        int h2 = tid / T1C, tq = tid - h2 * T1C;
        float mx = -1e30f;
#pragma unroll
        for (int j = 0; j < T1C; j++) mx = fmaxf(mx, s[h2][tq][j]);
        float sum = 0.f;
#pragma unroll
        for (int j = 0; j < T1C; j++) { float ex = expf(s[h2][tq][j] - mx); s[h2][tq][j] = ex; sum += ex; }
        float inv = 1.f / sum;
#pragma unroll
        for (int j = 0; j < T1C; j++) s[h2][tq][j] *= inv;
    }
    __syncthreads();
    int oc = hh * 32 + lane;
#pragma unroll
    for (int t = 0; t < T1C; t++) {
        float acc = 0.f;
#pragma unroll
        for (int tk = 0; tk < T1C; tk++) acc += s[hh][t][tk] * v[tk][oc];
        outb[((size_t)bn * T1C + t) * HHC + oc] = f2b(acc);
    }
}

// ---------------- transpose (+ t_re) ----------------

__global__ __launch_bounds__(256) void addtre_T_k(const float* __restrict__ h, const float* __restrict__ tre,
                                                  float* __restrict__ hBT, unsigned short* __restrict__ hBTb)
{
    int i = blockIdx.x * blockDim.x + threadIdx.x;
    if (i >= MROWS * HHC) return;
    int c = i & (HHC - 1);
    int row = i >> 7;
    int bt = row / NN, n = row - bt * NN;
    int b = bt / T1C, t = bt - b * T1C;
    float v = h[(((size_t)(b * NN + n)) * T1C + t) * HHC + c] + tre[t * HHC + c];
    hBT[i] = v;
    hBTb[i] = f2b(v);
}

__global__ __launch_bounds__(128) void lnT_k(const float* __restrict__ hBT, const float* __restrict__ g,
                                             const float* __restrict__ be, float* __restrict__ h,
                                             unsigned short* __restrict__ hb)
{
    int row = blockIdx.x;
    int tid = threadIdx.x;
    __shared__ float s2[2];
    int bt = row / NN, n = row - bt * NN;
    int b = bt / T1C, t = bt - b * T1C;
    float x = hBT[(size_t)row * HHC + tid];
    float m = blockSum128(x, s2) * (1.f / 128.f);
    float d = x - m;
    float v = blockSum128(d * d, s2) * (1.f / 128.f);
    float val = d * rsqrtf(v + EPSLN) * g[tid] + be[tid];
    size_t oidx = (((size_t)(b * NN + n)) * T1C + t) * HHC + tid;
    h[oidx] = val;
    hb[oidx] = f2b(val);
}

// ---------------- graph attention ----------------

__global__ __launch_bounds__(256) void emea_k(const float* __restrict__ e, const int* __restrict__ epos,
                                              const float* __restrict__ Wem, const float* __restrict__ bem,
                                              const float* __restrict__ Wea, const float* __restrict__ bea,
                                              float* __restrict__ emp1c, float* __restrict__ eawc)
{
    int r = blockIdx.x * blockDim.x + threadIdx.x;
    if (r >= EEC) return;
    float ev[DEC];
#pragma unroll
    for (int k = 0; k < DEC; k++) ev[k] = e[r * DEC + k];
    int pos = epos[r];
#pragma unroll
    for (int hh = 0; hh < NHD; hh++) {
        float a = bem[hh], b2 = bea[hh];
#pragma unroll
        for (int k = 0; k < DEC; k++) { a += ev[k] * Wem[k * NHD + hh]; b2 += ev[k] * Wea[k * NHD + hh]; }
        emp1c[pos * NHD + hh] = a + 1.f;
        eawc[pos * NHD + hh] = b2;
    }
}

// w = exp(score) in CSR order; 2 edges per iteration for MLP
__global__ __launch_bounds__(128) void score_k(const unsigned short* __restrict__ Q,
                                               const unsigned short* __restrict__ K,
                                               const int* __restrict__ dstCSR, const int* __restrict__ srcCSR,
                                               const float* __restrict__ emp1c, const float* __restrict__ eawc,
                                               float* __restrict__ w)
{
    int bt = blockIdx.y;
    int tid = threadIdx.x;
    int hh = tid & 3, isub = tid >> 2;
    size_t base = (size_t)bt * NN;
    int stride = gridDim.x * 32;
    for (int i = blockIdx.x * 32 + isub; i < EEC; i += 2 * stride) {
        int j = i + stride;
        bool hasj = j < EEC;
        int dn0 = dstCSR[i], sn0 = srcCSR[i];
        int dn1 = hasj ? dstCSR[j] : dn0;
        int sn1 = hasj ? srcCSR[j] : sn0;
        const uint4* q0 = (const uint4*)(Q + (base + dn0) * HHC + hh * 32);
        const uint4* k0 = (const uint4*)(K + (base + sn0) * HHC + hh * 32);
        const uint4* q1 = (const uint4*)(Q + (base + dn1) * HHC + hh * 32);
        const uint4* k1 = (const uint4*)(K + (base + sn1) * HHC + hh * 32);
        float acc0 = 0.f, acc1 = 0.f;
#pragma unroll
        for (int d = 0; d < 4; d++) {
            uint4 a0 = q0[d], b0 = k0[d], a1 = q1[d], b1 = k1[d];
            unsigned av0[4] = {a0.x, a0.y, a0.z, a0.w};
            unsigned bv0[4] = {b0.x, b0.y, b0.z, b0.w};
            unsigned av1[4] = {a1.x, a1.y, a1.z, a1.w};
            unsigned bv1[4] = {b1.x, b1.y, b1.z, b1.w};
#pragma unroll
            for (int jj = 0; jj < 4; jj++) {
                acc0 += __uint_as_float(av0[jj] << 16) * __uint_as_float(bv0[jj] << 16);
                acc0 += __uint_as_float(av0[jj] & 0xFFFF0000u) * __uint_as_float(bv0[jj] & 0xFFFF0000u);
                acc1 += __uint_as_float(av1[jj] << 16) * __uint_as_float(bv1[jj] << 16);
                acc1 += __uint_as_float(av1[jj] & 0xFFFF0000u) * __uint_as_float(bv1[jj] & 0xFFFF0000u);
            }
        }
        float sc0 = acc0 * SCALEQK * emp1c[i * NHD + hh] + eawc[i * NHD + hh];
        w[((size_t)bt * EEC + i) * NHD + hh] = expf(sc0);
        if (hasj) {
            float sc1 = acc1 * SCALEQK * emp1c[j * NHD + hh] + eawc[j * NHD + hh];
            w[((size_t)bt * EEC + j) * NHD + hh] = expf(sc1);
        }
    }
}

// weighted gather-sum over CSR; 4-wide unroll for MLP
__global__ __launch_bounds__(128) void agg_k(const unsigned short* __restrict__ V,
                                             const int* __restrict__ rowptr, const int* __restrict__ srcCSR,
                                             const float* __restrict__ w, unsigned short* __restrict__ outb)
{
    int blk = blockIdx.x;
    int bt = blk / NN, n = blk - bt * NN;
    int tid = threadIdx.x;
    int hh = tid >> 5, lane = tid & 31;
    size_t base = (size_t)bt * NN;
    int oc = hh * 32 + lane;
    const float* wp = w + (size_t)bt * EEC * NHD + hh;
    float den = 0.f, acc = 0.f;
    int s0 = rowptr[n], s1 = rowptr[n + 1];
    int i = s0;
    for (; i + 3 < s1; i += 4) {
        int sn0 = srcCSR[i], sn1 = srcCSR[i + 1], sn2 = srcCSR[i + 2], sn3 = srcCSR[i + 3];
        float w0 = wp[(size_t)i * NHD];
        float w1 = wp[(size_t)(i + 1) * NHD];
        float w2 = wp[(size_t)(i + 2) * NHD];
        float w3 = wp[(size_t)(i + 3) * NHD];
        float v0 = b2f(V[(base + sn0) * HHC + oc]);
        float v1 = b2f(V[(base + sn1) * HHC + oc]);
        float v2 = b2f(V[(base + sn2) * HHC + oc]);
        float v3 = b2f(V[(base + sn3) * HHC + oc]);
        acc += w0 * v0 + w1 * v1 + w2 * v2 + w3 * v3;
        den += (w0 + w1) + (w2 + w3);
    }
    for (; i < s1; i++) {
        int sn = srcCSR[i];
        float wv = wp[(size_t)i * NHD];
        acc += wv * b2f(V[(base + sn) * HHC + oc]);
        den += wv;
    }
    outb[(base + n) * HHC + oc] = f2b(acc / (den + 1e-9f));
}

__global__ __launch_bounds__(128) void hmean_k(const float* __restrict__ hBT, float* __restrict__ hmean)
{
    int n = blockIdx.x, c = threadIdx.x;
    float s = 0.f;
#pragma unroll
    for (int bt = 0; bt < BTC; bt++) s += hBT[((size_t)bt * NN + n) * HHC + c];
    hmean[n * HHC + c] = s * (1.f / BTC);
}

__global__ __launch_bounds__(256) void ein_k(const float* __restrict__ hmean, const int* __restrict__ dst,
                                             const int* __restrict__ src, const float* __restrict__ e,
                                             unsigned short* __restrict__ einb)
{
    int i = blockIdx.x * blockDim.x + threadIdx.x;
    if (i >= EEC * 288) return;
    int r = i / 288, j = i - r * 288;
    float v;
    if (j < HHC) v = hmean[dst[r] * HHC + j];
    else if (j < 2 * HHC) v = hmean[src[r] * HHC + (j - HHC)];
    else if (j < 2 * HHC + DEC) v = e[r * DEC + (j - 2 * HHC)];
    else v = 0.f;
    einb[i] = f2b(v);
}

__global__ __launch_bounds__(256) void eln_k(float* __restrict__ e, const float* __restrict__ emlp,
                                             const float* __restrict__ g, const float* __restrict__ be)
{
    int r = blockIdx.x * blockDim.x + threadIdx.x;
    if (r >= EEC) return;
    float x[DEC];
    float s = 0.f;
#pragma unroll
    for (int c = 0; c < DEC; c++) { x[c] = e[r * DEC + c] + emlp[r * DEC + c]; s += x[c]; }
    float m = s * (1.f / DEC);
    float v = 0.f;
#pragma unroll
    for (int c = 0; c < DEC; c++) { float d = x[c] - m; v += d * d; }
    v *= (1.f / DEC);
    float rstd = rsqrtf(v + EPSLN);
#pragma unroll
    for (int c = 0; c < DEC; c++) e[r * DEC + c] = (x[c] - m) * rstd * g[c] + be[c];
}

// ---------------- output head: one wave per row ----------------

__global__ __launch_bounds__(256) void out_k(const float* __restrict__ h, const float* __restrict__ Wout,
                                             const float* __restrict__ bout, float* __restrict__ out)
{
    int row = blockIdx.x * 4 + (threadIdx.x >> 6);
    int lane = threadIdx.x & 63;
    const float* hp = h + (size_t)row * HHC;
    float x0 = hp[lane], x1 = hp[lane + 64];
    float w00 = Wout[lane * 4 + 0], w01 = Wout[lane * 4 + 1];
    float w02 = Wout[lane * 4 + 2], w03 = Wout[lane * 4 + 3];
    float w10 = Wout[(lane + 64) * 4 + 0], w11 = Wout[(lane + 64) * 4 + 1];
    float w12 = Wout[(lane + 64) * 4 + 2], w13 = Wout[(lane + 64) * 4 + 3];
    float p0 = x0 * w00 + x1 * w10;
    float p1 = x0 * w01 + x1 * w11;
    float p2 = x0 * w02 + x1 * w12;
    float p3 = x0 * w03 + x1 * w13;
#pragma unroll
    for (int m = 32; m >= 1; m >>= 1) {
        p0 += __shfl_xor(p0, m, 64);
        p1 += __shfl_xor(p1, m, 64);
        p2 += __shfl_xor(p2, m, 64);
        p3 += __shfl_xor(p3, m, 64);
    }
    if (lane == 0) {
        float l0 = p0 + bout[0], l1 = p1 + bout[1], l2 = p2 + bout[2], l3 = p3 + bout[3];
        float mx = fmaxf(fmaxf(l0, l1), fmaxf(l2, l3));
        float e0 = expf(l0 - mx), e1 = expf(l1 - mx), e2 = expf(l2 - mx), e3 = expf(l3 - mx);
        float inv = 1.f / (e0 + e1 + e2 + e3);
        float4 o = {e0 * inv, e1 * inv, e2 * inv, e3 * inv};
        *(float4*)(out + (size_t)row * 4) = o;
    }
}

// ---------------- launch ----------------

extern "C" void kernel_launch(void* const* d_in, const int* in_sizes, int n_in,
                              void* d_out, int out_size, void* d_ws, size_t ws_size,
                              hipStream_t stream)
{
    const float* Xk      = (const float*)d_in[0];
    const float* temb    = (const float*)d_in[1];
    const float* stepemb = (const float*)d_in[2];
    const float* Wtr     = (const float*)d_in[3];
    const float* btr     = (const float*)d_in[4];
    const float* Win     = (const float*)d_in[5];
    const float* bin     = (const float*)d_in[6];
    const float* gin     = (const float*)d_in[7];
    const float* bein    = (const float*)d_in[8];
    const float* We      = (const float*)d_in[9];
    const float* bE      = (const float*)d_in[10];
    const float* aw      = (const float*)d_in[11];
    const float* ab      = (const float*)d_in[12];
    const float* ow      = (const float*)d_in[13];
    const float* ob      = (const float*)d_in[14];
    const float* tng     = (const float*)d_in[15];
    const float* tnb     = (const float*)d_in[16];
    const float* f1w     = (const float*)d_in[17];
    const float* f1b     = (const float*)d_in[18];
    const float* f2w     = (const float*)d_in[19];
    const float* f2b_    = (const float*)d_in[20];
    const float* fng     = (const float*)d_in[21];
    const float* fnb     = (const float*)d_in[22];
    const float* Wq      = (const float*)d_in[23];
    const float* Wk      = (const float*)d_in[24];
    const float* Wv      = (const float*)d_in[25];
    const float* Wo      = (const float*)d_in[26];
    const float* bo      = (const float*)d_in[27];
    const float* Wem     = (const float*)d_in[28];
    const float* bem     = (const float*)d_in[29];
    const float* Wea     = (const float*)d_in[30];
    const float* bea     = (const float*)d_in[31];
    const float* e1w     = (const float*)d_in[32];
    const float* e1b     = (const float*)d_in[33];
    const float* e2w     = (const float*)d_in[34];
    const float* e2b     = (const float*)d_in[35];
    const float* gng     = (const float*)d_in[36];
    const float* gnb     = (const float*)d_in[37];
    const float* eng     = (const float*)d_in[38];
    const float* enb     = (const float*)d_in[39];
    const float* Wout    = (const float*)d_in[40];
    const float* bout    = (const float*)d_in[41];
    const int*   kidx    = (const int*)d_in[42];
    const int*   eidx    = (const int*)d_in[43];
    float* outp = (float*)d_out;

    char* wsp = (char*)d_ws;
    auto alloc = [&](size_t nbytes) -> void* {
        void* p = (void*)wsp;
        wsp += (nbytes + 255) & ~(size_t)255;
        return p;
    };
    float* h     = (float*)alloc((size_t)MROWS * HHC * 4);
    unsigned short* hb = (unsigned short*)alloc((size_t)MROWS * HHC * 2);
    float* hBT   = (float*)alloc((size_t)MROWS * HHC * 4);
    unsigned short* hBTb = (unsigned short*)alloc((size_t)MROWS * HHC * 2);
    float* bufC  = (float*)alloc((size_t)MROWS * 384 * 4);
    unsigned short* bufDb = (unsigned short*)alloc((size_t)MROWS * HHC * 2);
    float* ebuf  = (float*)alloc((size_t)EEC * DEC * 4);
    float* emp1c = (float*)alloc((size_t)EEC * NHD * 4);
    float* eawc  = (float*)alloc((size_t)EEC * NHD * 4);
    float* emid  = (float*)alloc((size_t)EEC * 64 * 4);
    float* emlp  = (float*)alloc((size_t)EEC * DEC * 4);
    float* hmean = (float*)alloc((size_t)NN * HHC * 4);
    float* tre   = (float*)alloc((size_t)T1C * HHC * 4);
    float* wbuf  = (float*)alloc((size_t)BTC * EEC * NHD * 4);
    float* degmaxf = (float*)alloc(4);
    int* degi   = (int*)alloc((size_t)NN * 4);
    int* dst    = (int*)alloc((size_t)EEC * 4);
    int* srcA   = (int*)alloc((size_t)EEC * 4);
    int* srcCSR = (int*)alloc((size_t)EEC * 4);
    int* dstCSR = (int*)alloc((size_t)EEC * 4);
    int* epos   = (int*)alloc((size_t)EEC * 4);
    int* rowptr = (int*)alloc((size_t)(NN + 1) * 4);
    int* cursor = (int*)alloc((size_t)NN * 4);
    unsigned short* awP   = (unsigned short*)alloc((size_t)LLC * 384 * 128 * 2);
    unsigned short* owP   = (unsigned short*)alloc((size_t)LLC * 128 * 128 * 2);
    unsigned short* f1P   = (unsigned short*)alloc((size_t)LLC * 256 * 128 * 2);
    unsigned short* f2P   = (unsigned short*)alloc((size_t)LLC * 128 * 256 * 2);
    unsigned short* WqkvP = (unsigned short*)alloc((size_t)LLC * 384 * 128 * 2);
    unsigned short* WoP   = (unsigned short*)alloc((size_t)LLC * 128 * 128 * 2);
    unsigned short* e1T   = (unsigned short*)alloc((size_t)LLC * 64 * 288 * 2);

    unsigned short* bufCb = (unsigned short*)bufC;
    unsigned short* midb  = (unsigned short*)bufC;
    unsigned short* Qc    = (unsigned short*)bufC;
    unsigned short* Kc    = Qc + (size_t)MROWS * HHC;
    unsigned short* Vc    = Kc + (size_t)MROWS * HHC;
    unsigned short* einb  = (unsigned short*)bufC;

    {
        auto cwp = [&](const float* W, unsigned short* Bp, int K, int N, int noff, int Ntot) {
            int total = LLC * K * N;
            convwp_k<<<(total + 255) / 256, 256, 0, stream>>>(W, Bp, LLC, K, N, noff, Ntot);
        };
        cwp(aw,  awP, 128, 384, 0, 384);
        cwp(ow,  owP, 128, 128, 0, 128);
        cwp(f1w, f1P, 128, 256, 0, 256);
        cwp(f2w, f2P, 256, 128, 0, 128);
        cwp(Wq,  WqkvP, 128, 128, 0,   384);
        cwp(Wk,  WqkvP, 128, 128, 128, 384);
        cwp(Wv,  WqkvP, 128, 128, 256, 384);
        cwp(Wo,  WoP, 128, 128, 0, 128);
        int totalE1 = LLC * 64 * 288;
        convw_k<<<(totalE1 + 255) / 256, 256, 0, stream>>>(e1w, e1T, LLC, 272, 64, 288, 64 * 288, 0);
    }

    zero_deg_k<<<(NN + 255) / 256, 256, 0, stream>>>(degi);
    build_edges_k<<<(EEC + 255) / 256, 256, 0, stream>>>(eidx, dst, srcA, degi);
    scan_k<<<1, 256, 0, stream>>>(degi, rowptr, cursor, degmaxf);
    feat_k<<<(EEC + 255) / 256, 256, 0, stream>>>(dst, srcA, degi, degmaxf, cursor, srcCSR, dstCSR, epos, We, bE, ebuf);

    embed_k<<<MROWS, 128, 0, stream>>>(Xk, temb, Win, bin, gin, bein, stepemb, kidx, h, hb);
    tre_k<<<T1C, 128, 0, stream>>>(temb, Wtr, btr, tre);

    for (int l = 0; l < LLC; l++) {
        const unsigned short* awP_l   = awP   + (size_t)l * 384 * 128;
        const unsigned short* owP_l   = owP   + (size_t)l * 128 * 128;
        const unsigned short* f1P_l   = f1P   + (size_t)l * 256 * 128;
        const unsigned short* f2P_l   = f2P   + (size_t)l * 128 * 256;
        const unsigned short* WqkvP_l = WqkvP + (size_t)l * 384 * 128;
        const unsigned short* WoP_l   = WoP   + (size_t)l * 128 * 128;
        const unsigned short* e1T_l   = e1T   + (size_t)l * 64 * 288;
        const float* ab_l  = ab  + (size_t)l * 3 * HHC;
        const float* ob_l  = ob  + (size_t)l * HHC;
        const float* tng_l = tng + (size_t)l * HHC;
        const float* tnb_l = tnb + (size_t)l * HHC;
        const float* f1b_l = f1b + (size_t)l * 256;
        const float* f2b_l = f2b_ + (size_t)l * HHC;
        const float* fng_l = fng + (size_t)l * HHC;
        const float* fnb_l = fnb + (size_t)l * HHC;
        const float* bo_l  = bo  + (size_t)l * HHC;
        const float* Wem_l = Wem + (size_t)l * DEC * NHD;
        const float* bem_l = bem + (size_t)l * NHD;
        const float* Wea_l = Wea + (size_t)l * DEC * NHD;
        const float* bea_l = bea + (size_t)l * NHD;
        const float* e1b_l = e1b + (size_t)l * 64;
        const float* e2w_l = e2w + (size_t)l * 64 * DEC;
        const float* e2b_l = e2b + (size_t)l * DEC;
        const float* gng_l = gng + (size_t)l * HHC;
        const float* gnb_l = gnb + (size_t)l * HHC;
        const float* eng_l = eng + (size_t)l * DEC;
        const float* enb_l = enb + (size_t)l * DEC;

        // temporal attention (qkv in bf16)
        run_gemm2<128, 0, 2>(hb, awP_l, ab_l, nullptr, bufCb, nullptr, nullptr, nullptr, MROWS, 384, stream);
        temporal_attn_k<<<BBC * NN, 128, 0, stream>>>(bufCb, bufDb);
        run_gemm2<128, 3, 3>(bufDb, owP_l, ob_l, h, hb, h, tng_l, tnb_l, MROWS, 128, stream);
        // FFN
        run_gemm2<128, 1, 2>(hb, f1P_l, f1b_l, nullptr, midb, nullptr, nullptr, nullptr, MROWS, 256, stream);
        run_gemm2<256, 3, 1>(midb, f2P_l, f2b_l, h, nullptr, h, fng_l, fnb_l, MROWS, 128, stream);
        // + t_re, transpose to [BT, N, H]
        addtre_T_k<<<(MROWS * HHC + 255) / 256, 256, 0, stream>>>(h, tre, hBT, hBTb);
        // graph attention: fused QKV GEMM, split compact outputs
        run_gemm2<128, 0, 4>(hBTb, WqkvP_l, nullptr, nullptr, Qc, nullptr, nullptr, nullptr, MROWS, 384, stream);
        emea_k<<<(EEC + 255) / 256, 256, 0, stream>>>(ebuf, epos, Wem_l, bem_l, Wea_l, bea_l, emp1c, eawc);
        score_k<<<dim3(64, BTC), 128, 0, stream>>>(Qc, Kc, dstCSR, srcCSR, emp1c, eawc, wbuf);
        agg_k<<<BTC * NN, 128, 0, stream>>>(Vc, rowptr, srcCSR, wbuf, bufDb);
        run_gemm2<128, 2, 1>(bufDb, WoP_l, bo_l, hBT, nullptr, hBT, nullptr, nullptr, MROWS, 128, stream);
        // edge update
        hmean_k<<<NN, 128, 0, stream>>>(hBT, hmean);
        ein_k<<<(EEC * 288 + 255) / 256, 256, 0, stream>>>(hmean, dst, srcA, ebuf, einb);
        gemm_mfma_k<2, 1, 1><<<(EEC + 31) / 32, 256, 0, stream>>>(einb, e1T_l, e1b_l, emid, nullptr,
                                                                  nullptr, nullptr, nullptr, EEC, 288);
        gemm_k<0, 64><<<(EEC + 15) / 16, 128, 0, stream>>>(emid, e2w_l, e2b_l, emlp, EEC, DEC);
        eln_k<<<(EEC + 255) / 256, 256, 0, stream>>>(ebuf, emlp, eng_l, enb_l);
        // final LN + transpose back to [B,N,T1,H]
        lnT_k<<<BTC * NN, 128, 0, stream>>>(hBT, gng_l, gnb_l, h, hb);
    }

    out_k<<<MROWS / 4, 256, 0, stream>>>(h, Wout, bout, outp);
}

// Round 15
// 1505.367 us; speedup vs baseline: 1.1003x; 1.1003x over previous
//
#include <hip/hip_runtime.h>
#include <math.h>

#define NN 2000
#define T1C 12
#define BBC 2
#define HHC 128
#define NHD 4
#define DFD 32
#define LLC 4
#define DEC 16
#define TEC 16
#define CINC 12
#define E0C 32000
#define EEC 34000
#define BTC 24
#define MROWS 48000
#define EPSLN 1e-5f
#define SCALEQK 0.17677669529663687f

typedef __attribute__((ext_vector_type(8))) short short8;
typedef __attribute__((ext_vector_type(4))) float f32x4;

// ---------------- helpers ----------------

__device__ __forceinline__ unsigned short f2b(float f)
{
    unsigned u = __float_as_uint(f);
    return (unsigned short)((u + 0x7FFF + ((u >> 16) & 1)) >> 16);
}

__device__ __forceinline__ float b2f(unsigned short h)
{
    return __uint_as_float(((unsigned)h) << 16);
}

__device__ __forceinline__ float blockSum128(float v, volatile float* s2)
{
    for (int m = 32; m >= 1; m >>= 1) v += __shfl_xor(v, m, 64);
    int w = threadIdx.x >> 6;
    __syncthreads();
    if ((threadIdx.x & 63) == 0) s2[w] = v;
    __syncthreads();
    return s2[0] + s2[1];
}

// ---------------- weight conversions ----------------

__global__ __launch_bounds__(256) void convw_k(const float* __restrict__ W, unsigned short* __restrict__ WT,
                                               int LN_, int K, int N, int Kp, int ostride, int ooff)
{
    int idx = blockIdx.x * blockDim.x + threadIdx.x;
    int total = LN_ * N * Kp;
    if (idx >= total) return;
    int l = idx / (N * Kp);
    int r = idx - l * (N * Kp);
    int n = r / Kp;
    int k = r - n * Kp;
    WT[(size_t)l * ostride + (size_t)(ooff + n) * Kp + k] =
        (k < K) ? f2b(W[(size_t)l * K * N + (size_t)k * N + n]) : 0;
}

__global__ __launch_bounds__(256) void convwp_k(const float* __restrict__ W, unsigned short* __restrict__ Bp,
                                                int LN_, int K, int N, int noff, int Ntot)
{
    int idx = blockIdx.x * blockDim.x + threadIdx.x;
    int total = LN_ * K * N;
    if (idx >= total) return;
    int l = idx / (K * N);
    int r = idx - l * (K * N);
    int k = r / N;
    int n = r - k * N + noff;
    size_t off = (size_t)l * K * Ntot +
                 ((size_t)((n >> 4) * (K >> 5) + (k >> 5)) << 9) +
                 (((k >> 3) & 3) << 7) + ((n & 15) << 3) + (k & 7);
    Bp[off] = f2b(W[idx]);
}

// ---------------- gemm2: 128x128-tile LDS-staged MFMA GEMM ----------------

template<int K, int EPI, int OUTM>
__global__ __launch_bounds__(256) void gemm2_k(
    const unsigned short* __restrict__ A, const unsigned short* __restrict__ Bp,
    const float* __restrict__ bias, float* __restrict__ C, unsigned short* __restrict__ Cb,
    const float* __restrict__ res, const float* __restrict__ gam, const float* __restrict__ bet,
    int M, int Ntot)
{
    __shared__ unsigned short A_s[128 * 16 * 8];
    __shared__ float red2[2][128][2];

    int tid = threadIdx.x;
    int w = tid >> 6, lane = tid & 63;
    int wr = w & 1, wc = w >> 1;
    int quad = lane >> 4, lr = lane & 15;

    const unsigned short* abase = A + (size_t)blockIdx.x * 128 * K;
    int ntg0 = blockIdx.y * 8 + wc * 4;

    f32x4 acc[4][4];
#pragma unroll
    for (int mt = 0; mt < 4; mt++)
#pragma unroll
        for (int nt = 0; nt < 4; nt++) acc[mt][nt] = (f32x4){0.f, 0.f, 0.f, 0.f};

#pragma unroll
    for (int kb = 0; kb < K; kb += 128) {
        if (kb) __syncthreads();
#pragma unroll
        for (int j = 0; j < 8; j++) {
            int s = j * 256 + tid;
            int row = s >> 4, ks = s & 15;
            int ko = ks ^ (row & 15);
            uint4 d = *(const uint4*)(abase + (size_t)row * K + kb + ko * 8);
            *(uint4*)(A_s + s * 8) = d;
        }
        __syncthreads();
#pragma unroll
        for (int k0 = 0; k0 < 128; k0 += 32) {
            short8 af[4], bf[4];
#pragma unroll
            for (int mt = 0; mt < 4; mt++) {
                int row_l = wr * 64 + mt * 16 + lr;
                int koct = (k0 >> 3) + quad;
                int slot = row_l * 16 + (koct ^ lr);
                af[mt] = *(const short8*)(A_s + slot * 8);
            }
#pragma unroll
            for (int nt = 0; nt < 4; nt++) {
                size_t off = ((size_t)(ntg0 + nt) * (K >> 5) + ((kb + k0) >> 5)) * 512 + lane * 8;
                bf[nt] = *(const short8*)(Bp + off);
            }
#pragma unroll
            for (int mt = 0; mt < 4; mt++)
#pragma unroll
                for (int nt = 0; nt < 4; nt++)
                    acc[mt][nt] = __builtin_amdgcn_mfma_f32_16x16x32_bf16(af[mt], bf[nt], acc[mt][nt], 0, 0, 0);
        }
    }

    int rbase = blockIdx.x * 128 + wr * 64;
    int cbase = blockIdx.y * 128 + wc * 64;

    if constexpr (EPI != 3) {
#pragma unroll
        for (int mt = 0; mt < 4; mt++) {
#pragma unroll
            for (int nt = 0; nt < 4; nt++) {
                int colg = cbase + nt * 16 + lr;
                float bv = bias ? bias[colg] : 0.f;
#pragma unroll
                for (int i = 0; i < 4; i++) {
                    int row = rbase + mt * 16 + quad * 4 + i;
                    float x = acc[mt][nt][i] + bv;
                    if constexpr (EPI == 1) x = 0.5f * x * (1.f + erff(x * 0.70710678118654752f));
                    if constexpr (EPI == 2) x = res[(size_t)row * Ntot + colg] + x;
                    if constexpr (OUTM & 1) C[(size_t)row * Ntot + colg] = x;
                    if constexpr (OUTM & 4)
                        Cb[(size_t)blockIdx.y * M * 128 + (size_t)row * 128 + (wc * 64 + nt * 16 + lr)] = f2b(x);
                    else if constexpr (OUTM & 2)
                        Cb[(size_t)row * Ntot + colg] = f2b(x);
                }
            }
        }
    } else {
        float s[4][4], s2l[4][4];
#pragma unroll
        for (int mt = 0; mt < 4; mt++)
#pragma unroll
            for (int i = 0; i < 4; i++) { s[mt][i] = 0.f; s2l[mt][i] = 0.f; }
#pragma unroll
        for (int mt = 0; mt < 4; mt++) {
#pragma unroll
            for (int nt = 0; nt < 4; nt++) {
                int colg = cbase + nt * 16 + lr;
                float bv = bias[colg];
#pragma unroll
                for (int i = 0; i < 4; i++) {
                    int row = rbase + mt * 16 + quad * 4 + i;
                    float x = acc[mt][nt][i] + bv + res[(size_t)row * 128 + colg];
                    acc[mt][nt][i] = x;
                    s[mt][i] += x;
                    s2l[mt][i] += x * x;
                }
            }
        }
#pragma unroll
        for (int m = 1; m < 16; m <<= 1) {
#pragma unroll
            for (int mt = 0; mt < 4; mt++)
#pragma unroll
                for (int i = 0; i < 4; i++) {
                    s[mt][i]  += __shfl_xor(s[mt][i], m, 64);
                    s2l[mt][i] += __shfl_xor(s2l[mt][i], m, 64);
                }
        }
        if (lr == 0) {
#pragma unroll
            for (int mt = 0; mt < 4; mt++)
#pragma unroll
                for (int i = 0; i < 4; i++) {
                    int rl = wr * 64 + mt * 16 + quad * 4 + i;
                    red2[wc][rl][0] = s[mt][i];
                    red2[wc][rl][1] = s2l[mt][i];
                }
        }
        __syncthreads();
#pragma unroll
        for (int mt = 0; mt < 4; mt++) {
#pragma unroll
            for (int i = 0; i < 4; i++) {
                int rl = wr * 64 + mt * 16 + quad * 4 + i;
                float st  = red2[0][rl][0] + red2[1][rl][0];
                float s2t = red2[0][rl][1] + red2[1][rl][1];
                float mu = st * (1.f / 128.f);
                float rstd = rsqrtf(s2t * (1.f / 128.f) - mu * mu + EPSLN);
                int row = rbase + mt * 16 + quad * 4 + i;
#pragma unroll
                for (int nt = 0; nt < 4; nt++) {
                    int colg = cbase + nt * 16 + lr;
                    float y = (acc[mt][nt][i] - mu) * rstd * gam[colg] + bet[colg];
                    if constexpr (OUTM & 1) C[(size_t)row * 128 + colg] = y;
                    if constexpr (OUTM & 2) Cb[(size_t)row * 128 + colg] = f2b(y);
                }
            }
        }
    }
}

template<int K, int EPI, int OUTM>
static void run_gemm2(const unsigned short* A, const unsigned short* Bp, const float* bias,
                      float* C, unsigned short* Cb, const float* res, const float* g, const float* be,
                      int M, int Ntot, hipStream_t stream)
{
    dim3 grid(M / 128, Ntot / 128);
    gemm2_k<K, EPI, OUTM><<<grid, 256, 0, stream>>>(A, Bp, bias, C, Cb, res, g, be, M, Ntot);
}

// ---------------- old-style MFMA GEMM (e1: K=288, N=64, M=34000) ----------------

template<int NT, int EPI, int OUTM>
__global__ __launch_bounds__(256) void gemm_mfma_k(
    const unsigned short* __restrict__ A, const unsigned short* __restrict__ WT,
    const float* __restrict__ bias, float* __restrict__ C, unsigned short* __restrict__ Cb,
    const float* __restrict__ res, const float* __restrict__ gam, const float* __restrict__ bet,
    int M, int K)
{
    const int Nc = NT * 32;
    int tid = threadIdx.x;
    int w = tid >> 6, lane = tid & 63;
    int wr = w & 1, wc = w >> 1;
    int r0 = blockIdx.x * 32 + wr * 16;
    int c0 = wc * NT * 16;
    int lr = lane & 15;
    int kq = (lane >> 4) * 8;
    int arow = r0 + lr; if (arow >= M) arow = M - 1;
    const unsigned short* ap = A + (size_t)arow * K + kq;
    const unsigned short* wp = WT + (size_t)(c0 + lr) * K + kq;

    f32x4 acc[NT];
#pragma unroll
    for (int t = 0; t < NT; t++) acc[t] = (f32x4){0.f, 0.f, 0.f, 0.f};

    for (int k0 = 0; k0 < K; k0 += 32) {
        short8 a = *(const short8*)(ap + k0);
#pragma unroll
        for (int t = 0; t < NT; t++) {
            short8 b = *(const short8*)(wp + (size_t)t * 16 * K + k0);
            acc[t] = __builtin_amdgcn_mfma_f32_16x16x32_bf16(a, b, acc[t], 0, 0, 0);
        }
    }

    int orow0 = r0 + (lane >> 4) * 4;
#pragma unroll
    for (int t = 0; t < NT; t++) {
        int col = c0 + t * 16 + lr;
        float bv = bias ? bias[col] : 0.f;
#pragma unroll
        for (int i = 0; i < 4; i++) {
            int row = orow0 + i;
            if (row < M) {
                float x = acc[t][i] + bv;
                if constexpr (EPI == 1) x = 0.5f * x * (1.f + erff(x * 0.70710678118654752f));
                if constexpr (EPI == 2) x = res[(size_t)row * Nc + col] + x;
                if constexpr (OUTM & 1) C[(size_t)row * Nc + col] = x;
                if constexpr (OUTM & 2) Cb[(size_t)row * Nc + col] = f2b(x);
            }
        }
    }
}

// ---------------- fp32 fallback GEMM (small: e2) ----------------

template<int EPI, int K>
__global__ __launch_bounds__(128) void gemm_k(
    const float* __restrict__ A, const float* __restrict__ W,
    const float* __restrict__ bias, float* __restrict__ C,
    int M, int Nc)
{
    __shared__ float As[16 * K];
    int tid = threadIdx.x;
    int row0 = blockIdx.x * 16;
    for (int i = tid; i < 16 * K; i += 128) {
        int r = i / K, k = i - r * K;
        int row = row0 + r;
        As[i] = (row < M) ? A[(size_t)row * K + k] : 0.f;
    }
    __syncthreads();
    for (int c = tid; c < Nc; c += 128) {
        float acc[16];
#pragma unroll
        for (int r = 0; r < 16; r++) acc[r] = 0.f;
        const float* wp = W + c;
        for (int k = 0; k < K; k++) {
            float w = wp[(size_t)k * Nc];
#pragma unroll
            for (int r = 0; r < 16; r++) acc[r] += As[r * K + k] * w;
        }
        float bv = bias ? bias[c] : 0.f;
#pragma unroll
        for (int r = 0; r < 16; r++) {
            int row = row0 + r;
            if (row < M) C[(size_t)row * Nc + c] = acc[r] + bv;
        }
    }
}

// ---------------- graph precompute ----------------

__global__ __launch_bounds__(256) void zero_deg_k(int* __restrict__ degi)
{
    int i = blockIdx.x * blockDim.x + threadIdx.x;
    if (i < NN) degi[i] = 0;
}

__global__ __launch_bounds__(256) void build_edges_k(const int* __restrict__ eidx,
                                                     int* __restrict__ dst, int* __restrict__ src,
                                                     int* __restrict__ degi)
{
    int e = blockIdx.x * blockDim.x + threadIdx.x;
    if (e >= EEC) return;
    int d, s;
    if (e < E0C) { d = eidx[e]; s = eidx[E0C + e]; }
    else { d = e - E0C; s = e - E0C; }
    dst[e] = d;
    src[e] = s;
    atomicAdd(&degi[d], 1);
}

__global__ __launch_bounds__(256) void scan_k(const int* __restrict__ degi, int* __restrict__ rowptr,
                                              int* __restrict__ cursor, float* __restrict__ degmaxf)
{
    __shared__ int ssum[256];
    __shared__ int smx[256];
    int tid = threadIdx.x;
    int vals[8];
    int s = 0, mx = 0;
    int base = tid * 8;
#pragma unroll
    for (int j = 0; j < 8; j++) {
        int idx = base + j;
        int v = (idx < NN) ? degi[idx] : 0;
        vals[j] = v; s += v; mx = max(mx, v);
    }
    ssum[tid] = s; smx[tid] = mx;
    __syncthreads();
    for (int off = 1; off < 256; off <<= 1) {
        int t = (tid >= off) ? ssum[tid - off] : 0;
        __syncthreads();
        ssum[tid] += t;
        __syncthreads();
    }
    for (int off = 128; off > 0; off >>= 1) {
        if (tid < off) smx[tid] = max(smx[tid], smx[tid + off]);
        __syncthreads();
    }
    if (tid == 0) *degmaxf = fmaxf((float)smx[0], 1.f);
    int running = ssum[tid] - s;
#pragma unroll
    for (int j = 0; j < 8; j++) {
        int idx = base + j;
        if (idx < NN) { rowptr[idx] = running; cursor[idx] = running; running += vals[j]; }
    }
    if (tid == 255) rowptr[NN] = ssum[255];
}

__global__ __launch_bounds__(256) void feat_k(const int* __restrict__ dst, const int* __restrict__ src,
                                              const int* __restrict__ degi, const float* __restrict__ degmaxf,
                                              int* __restrict__ cursor, int* __restrict__ srcCSR,
                                              int* __restrict__ dstCSR, int* __restrict__ epos,
                                              const float* __restrict__ We, const float* __restrict__ bE,
                                              float* __restrict__ e)
{
    int ei = blockIdx.x * blockDim.x + threadIdx.x;
    if (ei >= EEC) return;
    int d = dst[ei], s = src[ei];
    int pos = atomicAdd(&cursor[d], 1);
    srcCSR[pos] = s;
    dstCSR[pos] = d;
    epos[ei] = pos;
    float dm = *degmaxf;
    float degd = (float)degi[d], degs = (float)degi[s];
    float f0 = 1.f / fmaxf(degd, 1.f);
    float f1 = degs / dm, f2 = degd / dm;
#pragma unroll
    for (int c = 0; c < DEC; c++)
        e[ei * DEC + c] = bE[c] + f0 * We[c] + f1 * We[DEC + c] + f2 * We[2 * DEC + c];
}

// ---------------- embedding ----------------

__global__ __launch_bounds__(128) void embed_k(const float* __restrict__ Xk, const float* __restrict__ temb,
                                               const float* __restrict__ Win, const float* __restrict__ bin,
                                               const float* __restrict__ g, const float* __restrict__ be,
                                               const float* __restrict__ stepemb, const int* __restrict__ kidx,
                                               float* __restrict__ h, unsigned short* __restrict__ hb)
{
    int row = blockIdx.x;
    int t = row % T1C;
    int bn = row / T1C;
    int b = bn / NN;
    __shared__ float x[28];
    __shared__ float s2[2];
    int tid = threadIdx.x;
    if (tid < CINC) x[tid] = Xk[(size_t)row * CINC + tid];
    else if (tid < 28) x[tid] = temb[t * TEC + (tid - CINC)];
    __syncthreads();
    float acc = bin[tid];
#pragma unroll
    for (int k = 0; k < 28; k++) acc += x[k] * Win[k * HHC + tid];
    float m = blockSum128(acc, s2) * (1.f / 128.f);
    float d = acc - m;
    float v = blockSum128(d * d, s2) * (1.f / 128.f);
    float val = d * rsqrtf(v + EPSLN) * g[tid] + be[tid] + stepemb[(size_t)kidx[b] * HHC + tid];
    h[(size_t)row * HHC + tid] = val;
    hb[(size_t)row * HHC + tid] = f2b(val);
}

__global__ __launch_bounds__(128) void tre_k(const float* __restrict__ temb, const float* __restrict__ Wtr,
                                             const float* __restrict__ btr, float* __restrict__ tre)
{
    int t = blockIdx.x, c = threadIdx.x;
    float acc = btr[c];
#pragma unroll
    for (int k = 0; k < TEC; k++) acc += temb[t * TEC + k] * Wtr[k * HHC + c];
    tre[t * HHC + c] = acc;
}

// ---------------- temporal attention (bf16 qkv input, scalar staging — round-13 proven) ----------------

__global__ __launch_bounds__(128) void temporal_attn_k(const unsigned short* __restrict__ qkvb,
                                                       unsigned short* __restrict__ outb)
{
    int bn = blockIdx.x;
    __shared__ float q[T1C][132], k[T1C][132], v[T1C][132];
    __shared__ float s[NHD][T1C][T1C];
    int tid = threadIdx.x;
    int hh = tid >> 5, lane = tid & 31;
    const unsigned short* base = qkvb + (size_t)bn * T1C * 384;
    for (int i = tid; i < T1C * 384; i += 128) {
        int t = i / 384, c = i - t * 384;
        float val = b2f(base[t * 384 + c]);
        if (c < 128) q[t][c] = val;
        else if (c < 256) k[t][c - 128] = val;
        else v[t][c - 256] = val;
    }
    __syncthreads();
    for (int idx = lane; idx < T1C * T1C; idx += 32) {
        int tq = idx / T1C, tk = idx - tq * T1C;
        float acc = 0.f;
        int off = hh * 32;
#pragma unroll
        for (int d = 0; d < 32; d++) acc += q[tq][off + d] * k[tk][off + d];
        s[hh][tq][tk] = acc * SCALEQK;
    }
    __syncthreads();
    if (tid < NHD * T1C) {
        int h2 = tid / T1C, tq = tid - h2 * T1C;
        float mx = -1e30f;
#pragma unroll
        for (int j = 0; j < T1C; j++) mx = fmaxf(mx, s[h2][tq][j]);
        float sum = 0.f;
#pragma unroll
        for (int j = 0; j < T1C; j++) { float ex = expf(s[h2][tq][j] - mx); s[h2][tq][j] = ex; sum += ex; }
        float inv = 1.f / sum;
#pragma unroll
        for (int j = 0; j < T1C; j++) s[h2][tq][j] *= inv;
    }
    __syncthreads();
    int oc = hh * 32 + lane;
#pragma unroll
    for (int t = 0; t < T1C; t++) {
        float acc = 0.f;
#pragma unroll
        for (int tk = 0; tk < T1C; tk++) acc += s[hh][t][tk] * v[tk][oc];
        outb[((size_t)bn * T1C + t) * HHC + oc] = f2b(acc);
    }
}

// ---------------- transpose (+ t_re) ----------------

__global__ __launch_bounds__(256) void addtre_T_k(const float* __restrict__ h, const float* __restrict__ tre,
                                                  float* __restrict__ hBT, unsigned short* __restrict__ hBTb)
{
    int i = blockIdx.x * blockDim.x + threadIdx.x;
    if (i >= MROWS * HHC) return;
    int c = i & (HHC - 1);
    int row = i >> 7;
    int bt = row / NN, n = row - bt * NN;
    int b = bt / T1C, t = bt - b * T1C;
    float v = h[(((size_t)(b * NN + n)) * T1C + t) * HHC + c] + tre[t * HHC + c];
    hBT[i] = v;
    hBTb[i] = f2b(v);
}

// lnT: one wave per row, shfl-only reduction, no barriers
__global__ __launch_bounds__(256) void lnT_k(const float* __restrict__ hBT, const float* __restrict__ g,
                                             const float* __restrict__ be, float* __restrict__ h,
                                             unsigned short* __restrict__ hb)
{
    int row = blockIdx.x * 4 + (threadIdx.x >> 6);   // bt*N + n
    int lane = threadIdx.x & 63;
    int bt = row / NN, n = row - bt * NN;
    int b = bt / T1C, t = bt - b * T1C;
    const float* rp = hBT + (size_t)row * HHC;
    float x0 = rp[lane], x1 = rp[lane + 64];
    float s = x0 + x1, s2 = x0 * x0 + x1 * x1;
#pragma unroll
    for (int m = 32; m >= 1; m >>= 1) {
        s  += __shfl_xor(s, m, 64);
        s2 += __shfl_xor(s2, m, 64);
    }
    float mu = s * (1.f / 128.f);
    float rstd = rsqrtf(s2 * (1.f / 128.f) - mu * mu + EPSLN);
    float v0 = (x0 - mu) * rstd * g[lane] + be[lane];
    float v1 = (x1 - mu) * rstd * g[lane + 64] + be[lane + 64];
    size_t obase = (((size_t)(b * NN + n)) * T1C + t) * HHC;
    h[obase + lane] = v0;
    h[obase + lane + 64] = v1;
    hb[obase + lane] = f2b(v0);
    hb[obase + lane + 64] = f2b(v1);
}

// ---------------- graph attention ----------------

__global__ __launch_bounds__(256) void emea_k(const float* __restrict__ e, const int* __restrict__ epos,
                                              const float* __restrict__ Wem, const float* __restrict__ bem,
                                              const float* __restrict__ Wea, const float* __restrict__ bea,
                                              float* __restrict__ emp1c, float* __restrict__ eawc)
{
    int r = blockIdx.x * blockDim.x + threadIdx.x;
    if (r >= EEC) return;
    float ev[DEC];
#pragma unroll
    for (int k = 0; k < DEC; k++) ev[k] = e[r * DEC + k];
    int pos = epos[r];
#pragma unroll
    for (int hh = 0; hh < NHD; hh++) {
        float a = bem[hh], b2 = bea[hh];
#pragma unroll
        for (int k = 0; k < DEC; k++) { a += ev[k] * Wem[k * NHD + hh]; b2 += ev[k] * Wea[k * NHD + hh]; }
        emp1c[pos * NHD + hh] = a + 1.f;
        eawc[pos * NHD + hh] = b2;
    }
}

// w = exp(score) in CSR order; 2 edges per iteration for MLP
__global__ __launch_bounds__(128) void score_k(const unsigned short* __restrict__ Q,
                                               const unsigned short* __restrict__ K,
                                               const int* __restrict__ dstCSR, const int* __restrict__ srcCSR,
                                               const float* __restrict__ emp1c, const float* __restrict__ eawc,
                                               float* __restrict__ w)
{
    int bt = blockIdx.y;
    int tid = threadIdx.x;
    int hh = tid & 3, isub = tid >> 2;
    size_t base = (size_t)bt * NN;
    int stride = gridDim.x * 32;
    for (int i = blockIdx.x * 32 + isub; i < EEC; i += 2 * stride) {
        int j = i + stride;
        bool hasj = j < EEC;
        int dn0 = dstCSR[i], sn0 = srcCSR[i];
        int dn1 = hasj ? dstCSR[j] : dn0;
        int sn1 = hasj ? srcCSR[j] : sn0;
        const uint4* q0 = (const uint4*)(Q + (base + dn0) * HHC + hh * 32);
        const uint4* k0 = (const uint4*)(K + (base + sn0) * HHC + hh * 32);
        const uint4* q1 = (const uint4*)(Q + (base + dn1) * HHC + hh * 32);
        const uint4* k1 = (const uint4*)(K + (base + sn1) * HHC + hh * 32);
        float acc0 = 0.f, acc1 = 0.f;
#pragma unroll
        for (int d = 0; d < 4; d++) {
            uint4 a0 = q0[d], b0 = k0[d], a1 = q1[d], b1 = k1[d];
            unsigned av0[4] = {a0.x, a0.y, a0.z, a0.w};
            unsigned bv0[4] = {b0.x, b0.y, b0.z, b0.w};
            unsigned av1[4] = {a1.x, a1.y, a1.z, a1.w};
            unsigned bv1[4] = {b1.x, b1.y, b1.z, b1.w};
#pragma unroll
            for (int jj = 0; jj < 4; jj++) {
                acc0 += __uint_as_float(av0[jj] << 16) * __uint_as_float(bv0[jj] << 16);
                acc0 += __uint_as_float(av0[jj] & 0xFFFF0000u) * __uint_as_float(bv0[jj] & 0xFFFF0000u);
                acc1 += __uint_as_float(av1[jj] << 16) * __uint_as_float(bv1[jj] << 16);
                acc1 += __uint_as_float(av1[jj] & 0xFFFF0000u) * __uint_as_float(bv1[jj] & 0xFFFF0000u);
            }
        }
        float sc0 = acc0 * SCALEQK * emp1c[i * NHD + hh] + eawc[i * NHD + hh];
        w[((size_t)bt * EEC + i) * NHD + hh] = expf(sc0);
        if (hasj) {
            float sc1 = acc1 * SCALEQK * emp1c[j * NHD + hh] + eawc[j * NHD + hh];
            w[((size_t)bt * EEC + j) * NHD + hh] = expf(sc1);
        }
    }
}

// weighted gather-sum over CSR; 4-wide unroll for MLP
__global__ __launch_bounds__(128) void agg_k(const unsigned short* __restrict__ V,
                                             const int* __restrict__ rowptr, const int* __restrict__ srcCSR,
                                             const float* __restrict__ w, unsigned short* __restrict__ outb)
{
    int blk = blockIdx.x;
    int bt = blk / NN, n = blk - bt * NN;
    int tid = threadIdx.x;
    int hh = tid >> 5, lane = tid & 31;
    size_t base = (size_t)bt * NN;
    int oc = hh * 32 + lane;
    const float* wp = w + (size_t)bt * EEC * NHD + hh;
    float den = 0.f, acc = 0.f;
    int s0 = rowptr[n], s1 = rowptr[n + 1];
    int i = s0;
    for (; i + 3 < s1; i += 4) {
        int sn0 = srcCSR[i], sn1 = srcCSR[i + 1], sn2 = srcCSR[i + 2], sn3 = srcCSR[i + 3];
        float w0 = wp[(size_t)i * NHD];
        float w1 = wp[(size_t)(i + 1) * NHD];
        float w2 = wp[(size_t)(i + 2) * NHD];
        float w3 = wp[(size_t)(i + 3) * NHD];
        float v0 = b2f(V[(base + sn0) * HHC + oc]);
        float v1 = b2f(V[(base + sn1) * HHC + oc]);
        float v2 = b2f(V[(base + sn2) * HHC + oc]);
        float v3 = b2f(V[(base + sn3) * HHC + oc]);
        acc += w0 * v0 + w1 * v1 + w2 * v2 + w3 * v3;
        den += (w0 + w1) + (w2 + w3);
    }
    for (; i < s1; i++) {
        int sn = srcCSR[i];
        float wv = wp[(size_t)i * NHD];
        acc += wv * b2f(V[(base + sn) * HHC + oc]);
        den += wv;
    }
    outb[(base + n) * HHC + oc] = f2b(acc / (den + 1e-9f));
}

__global__ __launch_bounds__(128) void hmean_k(const float* __restrict__ hBT, float* __restrict__ hmean)
{
    int n = blockIdx.x, c = threadIdx.x;
    float s = 0.f;
#pragma unroll
    for (int bt = 0; bt < BTC; bt++) s += hBT[((size_t)bt * NN + n) * HHC + c];
    hmean[n * HHC + c] = s * (1.f / BTC);
}

__global__ __launch_bounds__(256) void ein_k(const float* __restrict__ hmean, const int* __restrict__ dst,
                                             const int* __restrict__ src, const float* __restrict__ e,
                                             unsigned short* __restrict__ einb)
{
    int i = blockIdx.x * blockDim.x + threadIdx.x;
    if (i >= EEC * 288) return;
    int r = i / 288, j = i - r * 288;
    float v;
    if (j < HHC) v = hmean[dst[r] * HHC + j];
    else if (j < 2 * HHC) v = hmean[src[r] * HHC + (j - HHC)];
    else if (j < 2 * HHC + DEC) v = e[r * DEC + (j - 2 * HHC)];
    else v = 0.f;
    einb[i] = f2b(v);
}

__global__ __launch_bounds__(256) void eln_k(float* __restrict__ e, const float* __restrict__ emlp,
                                             const float* __restrict__ g, const float* __restrict__ be)
{
    int r = blockIdx.x * blockDim.x + threadIdx.x;
    if (r >= EEC) return;
    float x[DEC];
    float s = 0.f;
#pragma unroll
    for (int c = 0; c < DEC; c++) { x[c] = e[r * DEC + c] + emlp[r * DEC + c]; s += x[c]; }
    float m = s * (1.f / DEC);
    float v = 0.f;
#pragma unroll
    for (int c = 0; c < DEC; c++) { float d = x[c] - m; v += d * d; }
    v *= (1.f / DEC);
    float rstd = rsqrtf(v + EPSLN);
#pragma unroll
    for (int c = 0; c < DEC; c++) e[r * DEC + c] = (x[c] - m) * rstd * g[c] + be[c];
}

// ---------------- output head: one wave per row ----------------

__global__ __launch_bounds__(256) void out_k(const float* __restrict__ h, const float* __restrict__ Wout,
                                             const float* __restrict__ bout, float* __restrict__ out)
{
    int row = blockIdx.x * 4 + (threadIdx.x >> 6);
    int lane = threadIdx.x & 63;
    const float* hp = h + (size_t)row * HHC;
    float x0 = hp[lane], x1 = hp[lane + 64];
    float w00 = Wout[lane * 4 + 0], w01 = Wout[lane * 4 + 1];
    float w02 = Wout[lane * 4 + 2], w03 = Wout[lane * 4 + 3];
    float w10 = Wout[(lane + 64) * 4 + 0], w11 = Wout[(lane + 64) * 4 + 1];
    float w12 = Wout[(lane + 64) * 4 + 2], w13 = Wout[(lane + 64) * 4 + 3];
    float p0 = x0 * w00 + x1 * w10;
    float p1 = x0 * w01 + x1 * w11;
    float p2 = x0 * w02 + x1 * w12;
    float p3 = x0 * w03 + x1 * w13;
#pragma unroll
    for (int m = 32; m >= 1; m >>= 1) {
        p0 += __shfl_xor(p0, m, 64);
        p1 += __shfl_xor(p1, m, 64);
        p2 += __shfl_xor(p2, m, 64);
        p3 += __shfl_xor(p3, m, 64);
    }
    if (lane == 0) {
        float l0 = p0 + bout[0], l1 = p1 + bout[1], l2 = p2 + bout[2], l3 = p3 + bout[3];
        float mx = fmaxf(fmaxf(l0, l1), fmaxf(l2, l3));
        float e0 = expf(l0 - mx), e1 = expf(l1 - mx), e2 = expf(l2 - mx), e3 = expf(l3 - mx);
        float inv = 1.f / (e0 + e1 + e2 + e3);
        float4 o = {e0 * inv, e1 * inv, e2 * inv, e3 * inv};
        *(float4*)(out + (size_t)row * 4) = o;
    }
}

// ---------------- launch ----------------

extern "C" void kernel_launch(void* const* d_in, const int* in_sizes, int n_in,
                              void* d_out, int out_size, void* d_ws, size_t ws_size,
                              hipStream_t stream)
{
    const float* Xk      = (const float*)d_in[0];
    const float* temb    = (const float*)d_in[1];
    const float* stepemb = (const float*)d_in[2];
    const float* Wtr     = (const float*)d_in[3];
    const float* btr     = (const float*)d_in[4];
    const float* Win     = (const float*)d_in[5];
    const float* bin     = (const float*)d_in[6];
    const float* gin     = (const float*)d_in[7];
    const float* bein    = (const float*)d_in[8];
    const float* We      = (const float*)d_in[9];
    const float* bE      = (const float*)d_in[10];
    const float* aw      = (const float*)d_in[11];
    const float* ab      = (const float*)d_in[12];
    const float* ow      = (const float*)d_in[13];
    const float* ob      = (const float*)d_in[14];
    const float* tng     = (const float*)d_in[15];
    const float* tnb     = (const float*)d_in[16];
    const float* f1w     = (const float*)d_in[17];
    const float* f1b     = (const float*)d_in[18];
    const float* f2w     = (const float*)d_in[19];
    const float* f2b_    = (const float*)d_in[20];
    const float* fng     = (const float*)d_in[21];
    const float* fnb     = (const float*)d_in[22];
    const float* Wq      = (const float*)d_in[23];
    const float* Wk      = (const float*)d_in[24];
    const float* Wv      = (const float*)d_in[25];
    const float* Wo      = (const float*)d_in[26];
    const float* bo      = (const float*)d_in[27];
    const float* Wem     = (const float*)d_in[28];
    const float* bem     = (const float*)d_in[29];
    const float* Wea     = (const float*)d_in[30];
    const float* bea     = (const float*)d_in[31];
    const float* e1w     = (const float*)d_in[32];
    const float* e1b     = (const float*)d_in[33];
    const float* e2w     = (const float*)d_in[34];
    const float* e2b     = (const float*)d_in[35];
    const float* gng     = (const float*)d_in[36];
    const float* gnb     = (const float*)d_in[37];
    const float* eng     = (const float*)d_in[38];
    const float* enb     = (const float*)d_in[39];
    const float* Wout    = (const float*)d_in[40];
    const float* bout    = (const float*)d_in[41];
    const int*   kidx    = (const int*)d_in[42];
    const int*   eidx    = (const int*)d_in[43];
    float* outp = (float*)d_out;

    char* wsp = (char*)d_ws;
    auto alloc = [&](size_t nbytes) -> void* {
        void* p = (void*)wsp;
        wsp += (nbytes + 255) & ~(size_t)255;
        return p;
    };
    float* h     = (float*)alloc((size_t)MROWS * HHC * 4);
    unsigned short* hb = (unsigned short*)alloc((size_t)MROWS * HHC * 2);
    float* hBT   = (float*)alloc((size_t)MROWS * HHC * 4);
    unsigned short* hBTb = (unsigned short*)alloc((size_t)MROWS * HHC * 2);
    float* bufC  = (float*)alloc((size_t)MROWS * 384 * 4);
    unsigned short* bufDb = (unsigned short*)alloc((size_t)MROWS * HHC * 2);
    float* ebuf  = (float*)alloc((size_t)EEC * DEC * 4);
    float* emp1c = (float*)alloc((size_t)EEC * NHD * 4);
    float* eawc  = (float*)alloc((size_t)EEC * NHD * 4);
    float* emid  = (float*)alloc((size_t)EEC * 64 * 4);
    float* emlp  = (float*)alloc((size_t)EEC * DEC * 4);
    float* hmean = (float*)alloc((size_t)NN * HHC * 4);
    float* tre   = (float*)alloc((size_t)T1C * HHC * 4);
    float* wbuf  = (float*)alloc((size_t)BTC * EEC * NHD * 4);
    float* degmaxf = (float*)alloc(4);
    int* degi   = (int*)alloc((size_t)NN * 4);
    int* dst    = (int*)alloc((size_t)EEC * 4);
    int* srcA   = (int*)alloc((size_t)EEC * 4);
    int* srcCSR = (int*)alloc((size_t)EEC * 4);
    int* dstCSR = (int*)alloc((size_t)EEC * 4);
    int* epos   = (int*)alloc((size_t)EEC * 4);
    int* rowptr = (int*)alloc((size_t)(NN + 1) * 4);
    int* cursor = (int*)alloc((size_t)NN * 4);
    unsigned short* awP   = (unsigned short*)alloc((size_t)LLC * 384 * 128 * 2);
    unsigned short* owP   = (unsigned short*)alloc((size_t)LLC * 128 * 128 * 2);
    unsigned short* f1P   = (unsigned short*)alloc((size_t)LLC * 256 * 128 * 2);
    unsigned short* f2P   = (unsigned short*)alloc((size_t)LLC * 128 * 256 * 2);
    unsigned short* WqkvP = (unsigned short*)alloc((size_t)LLC * 384 * 128 * 2);
    unsigned short* WoP   = (unsigned short*)alloc((size_t)LLC * 128 * 128 * 2);
    unsigned short* e1T   = (unsigned short*)alloc((size_t)LLC * 64 * 288 * 2);

    unsigned short* bufCb = (unsigned short*)bufC;
    unsigned short* midb  = (unsigned short*)bufC;
    unsigned short* Qc    = (unsigned short*)bufC;
    unsigned short* Kc    = Qc + (size_t)MROWS * HHC;
    unsigned short* Vc    = Kc + (size_t)MROWS * HHC;
    unsigned short* einb  = (unsigned short*)bufC;

    {
        auto cwp = [&](const float* W, unsigned short* Bp, int K, int N, int noff, int Ntot) {
            int total = LLC * K * N;
            convwp_k<<<(total + 255) / 256, 256, 0, stream>>>(W, Bp, LLC, K, N, noff, Ntot);
        };
        cwp(aw,  awP, 128, 384, 0, 384);
        cwp(ow,  owP, 128, 128, 0, 128);
        cwp(f1w, f1P, 128, 256, 0, 256);
        cwp(f2w, f2P, 256, 128, 0, 128);
        cwp(Wq,  WqkvP, 128, 128, 0,   384);
        cwp(Wk,  WqkvP, 128, 128, 128, 384);
        cwp(Wv,  WqkvP, 128, 128, 256, 384);
        cwp(Wo,  WoP, 128, 128, 0, 128);
        int totalE1 = LLC * 64 * 288;
        convw_k<<<(totalE1 + 255) / 256, 256, 0, stream>>>(e1w, e1T, LLC, 272, 64, 288, 64 * 288, 0);
    }

    zero_deg_k<<<(NN + 255) / 256, 256, 0, stream>>>(degi);
    build_edges_k<<<(EEC + 255) / 256, 256, 0, stream>>>(eidx, dst, srcA, degi);
    scan_k<<<1, 256, 0, stream>>>(degi, rowptr, cursor, degmaxf);
    feat_k<<<(EEC + 255) / 256, 256, 0, stream>>>(dst, srcA, degi, degmaxf, cursor, srcCSR, dstCSR, epos, We, bE, ebuf);

    embed_k<<<MROWS, 128, 0, stream>>>(Xk, temb, Win, bin, gin, bein, stepemb, kidx, h, hb);
    tre_k<<<T1C, 128, 0, stream>>>(temb, Wtr, btr, tre);

    for (int l = 0; l < LLC; l++) {
        const unsigned short* awP_l   = awP   + (size_t)l * 384 * 128;
        const unsigned short* owP_l   = owP   + (size_t)l * 128 * 128;
        const unsigned short* f1P_l   = f1P   + (size_t)l * 256 * 128;
        const unsigned short* f2P_l   = f2P   + (size_t)l * 128 * 256;
        const unsigned short* WqkvP_l = WqkvP + (size_t)l * 384 * 128;
        const unsigned short* WoP_l   = WoP   + (size_t)l * 128 * 128;
        const unsigned short* e1T_l   = e1T   + (size_t)l * 64 * 288;
        const float* ab_l  = ab  + (size_t)l * 3 * HHC;
        const float* ob_l  = ob  + (size_t)l * HHC;
        const float* tng_l = tng + (size_t)l * HHC;
        const float* tnb_l = tnb + (size_t)l * HHC;
        const float* f1b_l = f1b + (size_t)l * 256;
        const float* f2b_l = f2b_ + (size_t)l * HHC;
        const float* fng_l = fng + (size_t)l * HHC;
        const float* fnb_l = fnb + (size_t)l * HHC;
        const float* bo_l  = bo  + (size_t)l * HHC;
        const float* Wem_l = Wem + (size_t)l * DEC * NHD;
        const float* bem_l = bem + (size_t)l * NHD;
        const float* Wea_l = Wea + (size_t)l * DEC * NHD;
        const float* bea_l = bea + (size_t)l * NHD;
        const float* e1b_l = e1b + (size_t)l * 64;
        const float* e2w_l = e2w + (size_t)l * 64 * DEC;
        const float* e2b_l = e2b + (size_t)l * DEC;
        const float* gng_l = gng + (size_t)l * HHC;
        const float* gnb_l = gnb + (size_t)l * HHC;
        const float* eng_l = eng + (size_t)l * DEC;
        const float* enb_l = enb + (size_t)l * DEC;

        // temporal attention (qkv in bf16)
        run_gemm2<128, 0, 2>(hb, awP_l, ab_l, nullptr, bufCb, nullptr, nullptr, nullptr, MROWS, 384, stream);
        temporal_attn_k<<<BBC * NN, 128, 0, stream>>>(bufCb, bufDb);
        run_gemm2<128, 3, 3>(bufDb, owP_l, ob_l, h, hb, h, tng_l, tnb_l, MROWS, 128, stream);
        // FFN
        run_gemm2<128, 1, 2>(hb, f1P_l, f1b_l, nullptr, midb, nullptr, nullptr, nullptr, MROWS, 256, stream);
        run_gemm2<256, 3, 1>(midb, f2P_l, f2b_l, h, nullptr, h, fng_l, fnb_l, MROWS, 128, stream);
        // + t_re, transpose to [BT, N, H]
        addtre_T_k<<<(MROWS * HHC + 255) / 256, 256, 0, stream>>>(h, tre, hBT, hBTb);
        // graph attention: fused QKV GEMM, split compact outputs
        run_gemm2<128, 0, 4>(hBTb, WqkvP_l, nullptr, nullptr, Qc, nullptr, nullptr, nullptr, MROWS, 384, stream);
        emea_k<<<(EEC + 255) / 256, 256, 0, stream>>>(ebuf, epos, Wem_l, bem_l, Wea_l, bea_l, emp1c, eawc);
        score_k<<<dim3(64, BTC), 128, 0, stream>>>(Qc, Kc, dstCSR, srcCSR, emp1c, eawc, wbuf);
        agg_k<<<BTC * NN, 128, 0, stream>>>(Vc, rowptr, srcCSR, wbuf, bufDb);
        run_gemm2<128, 2, 1>(bufDb, WoP_l, bo_l, hBT, nullptr, hBT, nullptr, nullptr, MROWS, 128, stream);
        // edge update
        hmean_k<<<NN, 128, 0, stream>>>(hBT, hmean);
        ein_k<<<(EEC * 288 + 255) / 256, 256, 0, stream>>>(hmean, dst, srcA, ebuf, einb);
        gemm_mfma_k<2, 1, 1><<<(EEC + 31) / 32, 256, 0, stream>>>(einb, e1T_l, e1b_l, emid, nullptr,
                                                                  nullptr, nullptr, nullptr, EEC, 288);
        gemm_k<0, 64><<<(EEC + 15) / 16, 128, 0, stream>>>(emid, e2w_l, e2b_l, emlp, EEC, DEC);
        eln_k<<<(EEC + 255) / 256, 256, 0, stream>>>(ebuf, emlp, eng_l, enb_l);
        // final LN + transpose back to [B,N,T1,H] (wave-per-row)
        lnT_k<<<MROWS / 4, 256, 0, stream>>>(hBT, gng_l, gnb_l, h, hb);
    }

    out_k<<<MROWS / 4, 256, 0, stream>>>(h, Wout, bout, outp);
}

// Round 16
// 1385.623 us; speedup vs baseline: 1.1953x; 1.0864x over previous
//
#include <hip/hip_runtime.h>
#include <math.h>

#define NN 2000
#define T1C 12
#define BBC 2
#define HHC 128
#define NHD 4
#define DFD 32
#define LLC 4
#define DEC 16
#define TEC 16
#define CINC 12
#define E0C 32000
#define EEC 34000
#define BTC 24
#define MROWS 48000
#define EPSLN 1e-5f
#define SCALEQK 0.17677669529663687f

typedef __attribute__((ext_vector_type(8))) short short8;
typedef __attribute__((ext_vector_type(4))) float f32x4;

// ---------------- helpers ----------------

__device__ __forceinline__ unsigned short f2b(float f)
{
    unsigned u = __float_as_uint(f);
    return (unsigned short)((u + 0x7FFF + ((u >> 16) & 1)) >> 16);
}

__device__ __forceinline__ float b2f(unsigned short h)
{
    return __uint_as_float(((unsigned)h) << 16);
}

__device__ __forceinline__ float blockSum128(float v, volatile float* s2)
{
    for (int m = 32; m >= 1; m >>= 1) v += __shfl_xor(v, m, 64);
    int w = threadIdx.x >> 6;
    __syncthreads();
    if ((threadIdx.x & 63) == 0) s2[w] = v;
    __syncthreads();
    return s2[0] + s2[1];
}

// ---------------- weight conversions ----------------

__global__ __launch_bounds__(256) void convw_k(const float* __restrict__ W, unsigned short* __restrict__ WT,
                                               int LN_, int K, int N, int Kp, int ostride, int ooff)
{
    int idx = blockIdx.x * blockDim.x + threadIdx.x;
    int total = LN_ * N * Kp;
    if (idx >= total) return;
    int l = idx / (N * Kp);
    int r = idx - l * (N * Kp);
    int n = r / Kp;
    int k = r - n * Kp;
    WT[(size_t)l * ostride + (size_t)(ooff + n) * Kp + k] =
        (k < K) ? f2b(W[(size_t)l * K * N + (size_t)k * N + n]) : 0;
}

__global__ __launch_bounds__(256) void convwp_k(const float* __restrict__ W, unsigned short* __restrict__ Bp,
                                                int LN_, int K, int N, int noff, int Ntot)
{
    int idx = blockIdx.x * blockDim.x + threadIdx.x;
    int total = LN_ * K * N;
    if (idx >= total) return;
    int l = idx / (K * N);
    int r = idx - l * (K * N);
    int k = r / N;
    int n = r - k * N + noff;
    size_t off = (size_t)l * K * Ntot +
                 ((size_t)((n >> 4) * (K >> 5) + (k >> 5)) << 9) +
                 (((k >> 3) & 3) << 7) + ((n & 15) << 3) + (k & 7);
    Bp[off] = f2b(W[idx]);
}

// ---------------- gemm2: 128x128-tile LDS-staged MFMA GEMM ----------------

template<int K, int EPI, int OUTM>
__global__ __launch_bounds__(256) void gemm2_k(
    const unsigned short* __restrict__ A, const unsigned short* __restrict__ Bp,
    const float* __restrict__ bias, float* __restrict__ C, unsigned short* __restrict__ Cb,
    const float* __restrict__ res, const float* __restrict__ gam, const float* __restrict__ bet,
    int M, int Ntot)
{
    __shared__ unsigned short A_s[128 * 16 * 8];
    __shared__ float red2[2][128][2];

    int tid = threadIdx.x;
    int w = tid >> 6, lane = tid & 63;
    int wr = w & 1, wc = w >> 1;
    int quad = lane >> 4, lr = lane & 15;

    const unsigned short* abase = A + (size_t)blockIdx.x * 128 * K;
    int ntg0 = blockIdx.y * 8 + wc * 4;

    f32x4 acc[4][4];
#pragma unroll
    for (int mt = 0; mt < 4; mt++)
#pragma unroll
        for (int nt = 0; nt < 4; nt++) acc[mt][nt] = (f32x4){0.f, 0.f, 0.f, 0.f};

#pragma unroll
    for (int kb = 0; kb < K; kb += 128) {
        if (kb) __syncthreads();
#pragma unroll
        for (int j = 0; j < 8; j++) {
            int s = j * 256 + tid;
            int row = s >> 4, ks = s & 15;
            int ko = ks ^ (row & 15);
            uint4 d = *(const uint4*)(abase + (size_t)row * K + kb + ko * 8);
            *(uint4*)(A_s + s * 8) = d;
        }
        __syncthreads();
#pragma unroll
        for (int k0 = 0; k0 < 128; k0 += 32) {
            short8 af[4], bf[4];
#pragma unroll
            for (int mt = 0; mt < 4; mt++) {
                int row_l = wr * 64 + mt * 16 + lr;
                int koct = (k0 >> 3) + quad;
                int slot = row_l * 16 + (koct ^ lr);
                af[mt] = *(const short8*)(A_s + slot * 8);
            }
#pragma unroll
            for (int nt = 0; nt < 4; nt++) {
                size_t off = ((size_t)(ntg0 + nt) * (K >> 5) + ((kb + k0) >> 5)) * 512 + lane * 8;
                bf[nt] = *(const short8*)(Bp + off);
            }
#pragma unroll
            for (int mt = 0; mt < 4; mt++)
#pragma unroll
                for (int nt = 0; nt < 4; nt++)
                    acc[mt][nt] = __builtin_amdgcn_mfma_f32_16x16x32_bf16(af[mt], bf[nt], acc[mt][nt], 0, 0, 0);
        }
    }

    int rbase = blockIdx.x * 128 + wr * 64;
    int cbase = blockIdx.y * 128 + wc * 64;

    if constexpr (EPI != 3) {
#pragma unroll
        for (int mt = 0; mt < 4; mt++) {
#pragma unroll
            for (int nt = 0; nt < 4; nt++) {
                int colg = cbase + nt * 16 + lr;
                float bv = bias ? bias[colg] : 0.f;
#pragma unroll
                for (int i = 0; i < 4; i++) {
                    int row = rbase + mt * 16 + quad * 4 + i;
                    float x = acc[mt][nt][i] + bv;
                    if constexpr (EPI == 1) x = 0.5f * x * (1.f + erff(x * 0.70710678118654752f));
                    if constexpr (EPI == 2) x = res[(size_t)row * Ntot + colg] + x;
                    if constexpr (OUTM & 1) C[(size_t)row * Ntot + colg] = x;
                    if constexpr (OUTM & 4)
                        Cb[(size_t)blockIdx.y * M * 128 + (size_t)row * 128 + (wc * 64 + nt * 16 + lr)] = f2b(x);
                    else if constexpr (OUTM & 2)
                        Cb[(size_t)row * Ntot + colg] = f2b(x);
                }
            }
        }
    } else {
        float s[4][4], s2l[4][4];
#pragma unroll
        for (int mt = 0; mt < 4; mt++)
#pragma unroll
            for (int i = 0; i < 4; i++) { s[mt][i] = 0.f; s2l[mt][i] = 0.f; }
#pragma unroll
        for (int mt = 0; mt < 4; mt++) {
#pragma unroll
            for (int nt = 0; nt < 4; nt++) {
                int colg = cbase + nt * 16 + lr;
                float bv = bias[colg];
#pragma unroll
                for (int i = 0; i < 4; i++) {
                    int row = rbase + mt * 16 + quad * 4 + i;
                    float x = acc[mt][nt][i] + bv + res[(size_t)row * 128 + colg];
                    acc[mt][nt][i] = x;
                    s[mt][i] += x;
                    s2l[mt][i] += x * x;
                }
            }
        }
#pragma unroll
        for (int m = 1; m < 16; m <<= 1) {
#pragma unroll
            for (int mt = 0; mt < 4; mt++)
#pragma unroll
                for (int i = 0; i < 4; i++) {
                    s[mt][i]  += __shfl_xor(s[mt][i], m, 64);
                    s2l[mt][i] += __shfl_xor(s2l[mt][i], m, 64);
                }
        }
        if (lr == 0) {
#pragma unroll
            for (int mt = 0; mt < 4; mt++)
#pragma unroll
                for (int i = 0; i < 4; i++) {
                    int rl = wr * 64 + mt * 16 + quad * 4 + i;
                    red2[wc][rl][0] = s[mt][i];
                    red2[wc][rl][1] = s2l[mt][i];
                }
        }
        __syncthreads();
#pragma unroll
        for (int mt = 0; mt < 4; mt++) {
#pragma unroll
            for (int i = 0; i < 4; i++) {
                int rl = wr * 64 + mt * 16 + quad * 4 + i;
                float st  = red2[0][rl][0] + red2[1][rl][0];
                float s2t = red2[0][rl][1] + red2[1][rl][1];
                float mu = st * (1.f / 128.f);
                float rstd = rsqrtf(s2t * (1.f / 128.f) - mu * mu + EPSLN);
                int row = rbase + mt * 16 + quad * 4 + i;
#pragma unroll
                for (int nt = 0; nt < 4; nt++) {
                    int colg = cbase + nt * 16 + lr;
                    float y = (acc[mt][nt][i] - mu) * rstd * gam[colg] + bet[colg];
                    if constexpr (OUTM & 1) C[(size_t)row * 128 + colg] = y;
                    if constexpr (OUTM & 2) Cb[(size_t)row * 128 + colg] = f2b(y);
                }
            }
        }
    }
}

template<int K, int EPI, int OUTM>
static void run_gemm2(const unsigned short* A, const unsigned short* Bp, const float* bias,
                      float* C, unsigned short* Cb, const float* res, const float* g, const float* be,
                      int M, int Ntot, hipStream_t stream)
{
    dim3 grid(M / 128, Ntot / 128);
    gemm2_k<K, EPI, OUTM><<<grid, 256, 0, stream>>>(A, Bp, bias, C, Cb, res, g, be, M, Ntot);
}

// ---------------- old-style MFMA GEMM (e1: K=288, N=64, M=34000) ----------------

template<int NT, int EPI, int OUTM>
__global__ __launch_bounds__(256) void gemm_mfma_k(
    const unsigned short* __restrict__ A, const unsigned short* __restrict__ WT,
    const float* __restrict__ bias, float* __restrict__ C, unsigned short* __restrict__ Cb,
    const float* __restrict__ res, const float* __restrict__ gam, const float* __restrict__ bet,
    int M, int K)
{
    const int Nc = NT * 32;
    int tid = threadIdx.x;
    int w = tid >> 6, lane = tid & 63;
    int wr = w & 1, wc = w >> 1;
    int r0 = blockIdx.x * 32 + wr * 16;
    int c0 = wc * NT * 16;
    int lr = lane & 15;
    int kq = (lane >> 4) * 8;
    int arow = r0 + lr; if (arow >= M) arow = M - 1;
    const unsigned short* ap = A + (size_t)arow * K + kq;
    const unsigned short* wp = WT + (size_t)(c0 + lr) * K + kq;

    f32x4 acc[NT];
#pragma unroll
    for (int t = 0; t < NT; t++) acc[t] = (f32x4){0.f, 0.f, 0.f, 0.f};

    for (int k0 = 0; k0 < K; k0 += 32) {
        short8 a = *(const short8*)(ap + k0);
#pragma unroll
        for (int t = 0; t < NT; t++) {
            short8 b = *(const short8*)(wp + (size_t)t * 16 * K + k0);
            acc[t] = __builtin_amdgcn_mfma_f32_16x16x32_bf16(a, b, acc[t], 0, 0, 0);
        }
    }

    int orow0 = r0 + (lane >> 4) * 4;
#pragma unroll
    for (int t = 0; t < NT; t++) {
        int col = c0 + t * 16 + lr;
        float bv = bias ? bias[col] : 0.f;
#pragma unroll
        for (int i = 0; i < 4; i++) {
            int row = orow0 + i;
            if (row < M) {
                float x = acc[t][i] + bv;
                if constexpr (EPI == 1) x = 0.5f * x * (1.f + erff(x * 0.70710678118654752f));
                if constexpr (EPI == 2) x = res[(size_t)row * Nc + col] + x;
                if constexpr (OUTM & 1) C[(size_t)row * Nc + col] = x;
                if constexpr (OUTM & 2) Cb[(size_t)row * Nc + col] = f2b(x);
            }
        }
    }
}

// ---------------- fp32 fallback GEMM (small: e2) ----------------

template<int EPI, int K>
__global__ __launch_bounds__(128) void gemm_k(
    const float* __restrict__ A, const float* __restrict__ W,
    const float* __restrict__ bias, float* __restrict__ C,
    int M, int Nc)
{
    __shared__ float As[16 * K];
    int tid = threadIdx.x;
    int row0 = blockIdx.x * 16;
    for (int i = tid; i < 16 * K; i += 128) {
        int r = i / K, k = i - r * K;
        int row = row0 + r;
        As[i] = (row < M) ? A[(size_t)row * K + k] : 0.f;
    }
    __syncthreads();
    for (int c = tid; c < Nc; c += 128) {
        float acc[16];
#pragma unroll
        for (int r = 0; r < 16; r++) acc[r] = 0.f;
        const float* wp = W + c;
        for (int k = 0; k < K; k++) {
            float w = wp[(size_t)k * Nc];
#pragma unroll
            for (int r = 0; r < 16; r++) acc[r] += As[r * K + k] * w;
        }
        float bv = bias ? bias[c] : 0.f;
#pragma unroll
        for (int r = 0; r < 16; r++) {
            int row = row0 + r;
            if (row < M) C[(size_t)row * Nc + c] = acc[r] + bv;
        }
    }
}

// ---------------- graph precompute ----------------

__global__ __launch_bounds__(256) void zero_deg_k(int* __restrict__ degi)
{
    int i = blockIdx.x * blockDim.x + threadIdx.x;
    if (i < NN) degi[i] = 0;
}

__global__ __launch_bounds__(256) void build_edges_k(const int* __restrict__ eidx,
                                                     int* __restrict__ dst, int* __restrict__ src,
                                                     int* __restrict__ degi)
{
    int e = blockIdx.x * blockDim.x + threadIdx.x;
    if (e >= EEC) return;
    int d, s;
    if (e < E0C) { d = eidx[e]; s = eidx[E0C + e]; }
    else { d = e - E0C; s = e - E0C; }
    dst[e] = d;
    src[e] = s;
    atomicAdd(&degi[d], 1);
}

__global__ __launch_bounds__(256) void scan_k(const int* __restrict__ degi, int* __restrict__ rowptr,
                                              int* __restrict__ cursor, float* __restrict__ degmaxf)
{
    __shared__ int ssum[256];
    __shared__ int smx[256];
    int tid = threadIdx.x;
    int vals[8];
    int s = 0, mx = 0;
    int base = tid * 8;
#pragma unroll
    for (int j = 0; j < 8; j++) {
        int idx = base + j;
        int v = (idx < NN) ? degi[idx] : 0;
        vals[j] = v; s += v; mx = max(mx, v);
    }
    ssum[tid] = s; smx[tid] = mx;
    __syncthreads();
    for (int off = 1; off < 256; off <<= 1) {
        int t = (tid >= off) ? ssum[tid - off] : 0;
        __syncthreads();
        ssum[tid] += t;
        __syncthreads();
    }
    for (int off = 128; off > 0; off >>= 1) {
        if (tid < off) smx[tid] = max(smx[tid], smx[tid + off]);
        __syncthreads();
    }
    if (tid == 0) *degmaxf = fmaxf((float)smx[0], 1.f);
    int running = ssum[tid] - s;
#pragma unroll
    for (int j = 0; j < 8; j++) {
        int idx = base + j;
        if (idx < NN) { rowptr[idx] = running; cursor[idx] = running; running += vals[j]; }
    }
    if (tid == 255) rowptr[NN] = ssum[255];
}

__global__ __launch_bounds__(256) void feat_k(const int* __restrict__ dst, const int* __restrict__ src,
                                              const int* __restrict__ degi, const float* __restrict__ degmaxf,
                                              int* __restrict__ cursor, int* __restrict__ srcCSR,
                                              int* __restrict__ dstCSR, int* __restrict__ epos,
                                              const float* __restrict__ We, const float* __restrict__ bE,
                                              float* __restrict__ e)
{
    int ei = blockIdx.x * blockDim.x + threadIdx.x;
    if (ei >= EEC) return;
    int d = dst[ei], s = src[ei];
    int pos = atomicAdd(&cursor[d], 1);
    srcCSR[pos] = s;
    dstCSR[pos] = d;
    epos[ei] = pos;
    float dm = *degmaxf;
    float degd = (float)degi[d], degs = (float)degi[s];
    float f0 = 1.f / fmaxf(degd, 1.f);
    float f1 = degs / dm, f2 = degd / dm;
#pragma unroll
    for (int c = 0; c < DEC; c++)
        e[ei * DEC + c] = bE[c] + f0 * We[c] + f1 * We[DEC + c] + f2 * We[2 * DEC + c];
}

// ---------------- embedding ----------------

__global__ __launch_bounds__(128) void embed_k(const float* __restrict__ Xk, const float* __restrict__ temb,
                                               const float* __restrict__ Win, const float* __restrict__ bin,
                                               const float* __restrict__ g, const float* __restrict__ be,
                                               const float* __restrict__ stepemb, const int* __restrict__ kidx,
                                               float* __restrict__ h, unsigned short* __restrict__ hb)
{
    int row = blockIdx.x;
    int t = row % T1C;
    int bn = row / T1C;
    int b = bn / NN;
    __shared__ float x[28];
    __shared__ float s2[2];
    int tid = threadIdx.x;
    if (tid < CINC) x[tid] = Xk[(size_t)row * CINC + tid];
    else if (tid < 28) x[tid] = temb[t * TEC + (tid - CINC)];
    __syncthreads();
    float acc = bin[tid];
#pragma unroll
    for (int k = 0; k < 28; k++) acc += x[k] * Win[k * HHC + tid];
    float m = blockSum128(acc, s2) * (1.f / 128.f);
    float d = acc - m;
    float v = blockSum128(d * d, s2) * (1.f / 128.f);
    float val = d * rsqrtf(v + EPSLN) * g[tid] + be[tid] + stepemb[(size_t)kidx[b] * HHC + tid];
    h[(size_t)row * HHC + tid] = val;
    hb[(size_t)row * HHC + tid] = f2b(val);
}

__global__ __launch_bounds__(128) void tre_k(const float* __restrict__ temb, const float* __restrict__ Wtr,
                                             const float* __restrict__ btr, float* __restrict__ tre)
{
    int t = blockIdx.x, c = threadIdx.x;
    float acc = btr[c];
#pragma unroll
    for (int k = 0; k < TEC; k++) acc += temb[t * TEC + k] * Wtr[k * HHC + c];
    tre[t * HHC + c] = acc;
}

// ---------------- temporal attention: raw-bf16 LDS staging ----------------
// qkv kept as bf16 in LDS (rows padded to 408 shorts); staging = plain uint4 copies.

__global__ __launch_bounds__(128) void temporal_attn_k(const unsigned short* __restrict__ qkvb,
                                                       unsigned short* __restrict__ outb)
{
    int bn = blockIdx.x;
    __shared__ unsigned short qkv_s[T1C][408];   // [t][c], c in 0..383 (q:0-127, k:128-255, v:256-383)
    __shared__ float s[NHD][T1C][T1C];
    int tid = threadIdx.x;
    int hh = tid >> 5, lane = tid & 31;
    const unsigned short* base = qkvb + (size_t)bn * T1C * 384;
    // 576 chunks of 8 bf16; chunk never straddles a row (48 chunks/row)
    for (int cIdx = tid; cIdx < 576; cIdx += 128) {
        uint4 d = *(const uint4*)(base + cIdx * 8);
        int t = cIdx / 48;
        int c0 = (cIdx - t * 48) * 8;
        *(uint4*)(&qkv_s[t][c0]) = d;
    }
    __syncthreads();
    // QK^T per head
    for (int idx = lane; idx < T1C * T1C; idx += 32) {
        int tq = idx / T1C, tk = idx - tq * T1C;
        const unsigned* qp = (const unsigned*)&qkv_s[tq][hh * 32];
        const unsigned* kp = (const unsigned*)&qkv_s[tk][128 + hh * 32];
        float acc = 0.f;
#pragma unroll
        for (int d = 0; d < 16; d++) {
            unsigned a = qp[d], b = kp[d];
            acc += __uint_as_float(a << 16) * __uint_as_float(b << 16);
            acc += __uint_as_float(a & 0xFFFF0000u) * __uint_as_float(b & 0xFFFF0000u);
        }
        s[hh][tq][tk] = acc * SCALEQK;
    }
    __syncthreads();
    if (tid < NHD * T1C) {
        int h2 = tid / T1C, tq = tid - h2 * T1C;
        float mx = -1e30f;
#pragma unroll
        for (int j = 0; j < T1C; j++) mx = fmaxf(mx, s[h2][tq][j]);
        float sum = 0.f;
#pragma unroll
        for (int j = 0; j < T1C; j++) { float ex = expf(s[h2][tq][j] - mx); s[h2][tq][j] = ex; sum += ex; }
        float inv = 1.f / sum;
#pragma unroll
        for (int j = 0; j < T1C; j++) s[h2][tq][j] *= inv;
    }
    __syncthreads();
    int oc = hh * 32 + lane;
#pragma unroll
    for (int t = 0; t < T1C; t++) {
        float acc = 0.f;
#pragma unroll
        for (int tk = 0; tk < T1C; tk++) acc += s[hh][t][tk] * b2f(qkv_s[tk][256 + oc]);
        outb[((size_t)bn * T1C + t) * HHC + oc] = f2b(acc);
    }
}

// ---------------- transpose (+ t_re) ----------------

__global__ __launch_bounds__(256) void addtre_T_k(const float* __restrict__ h, const float* __restrict__ tre,
                                                  float* __restrict__ hBT, unsigned short* __restrict__ hBTb)
{
    int i = blockIdx.x * blockDim.x + threadIdx.x;
    if (i >= MROWS * HHC) return;
    int c = i & (HHC - 1);
    int row = i >> 7;
    int bt = row / NN, n = row - bt * NN;
    int b = bt / T1C, t = bt - b * T1C;
    float v = h[(((size_t)(b * NN + n)) * T1C + t) * HHC + c] + tre[t * HHC + c];
    hBT[i] = v;
    hBTb[i] = f2b(v);
}

// lnT: one wave per row, shfl-only reduction, no barriers
__global__ __launch_bounds__(256) void lnT_k(const float* __restrict__ hBT, const float* __restrict__ g,
                                             const float* __restrict__ be, float* __restrict__ h,
                                             unsigned short* __restrict__ hb)
{
    int row = blockIdx.x * 4 + (threadIdx.x >> 6);   // bt*N + n
    int lane = threadIdx.x & 63;
    int bt = row / NN, n = row - bt * NN;
    int b = bt / T1C, t = bt - b * T1C;
    const float* rp = hBT + (size_t)row * HHC;
    float x0 = rp[lane], x1 = rp[lane + 64];
    float s = x0 + x1, s2 = x0 * x0 + x1 * x1;
#pragma unroll
    for (int m = 32; m >= 1; m >>= 1) {
        s  += __shfl_xor(s, m, 64);
        s2 += __shfl_xor(s2, m, 64);
    }
    float mu = s * (1.f / 128.f);
    float rstd = rsqrtf(s2 * (1.f / 128.f) - mu * mu + EPSLN);
    float v0 = (x0 - mu) * rstd * g[lane] + be[lane];
    float v1 = (x1 - mu) * rstd * g[lane + 64] + be[lane + 64];
    size_t obase = (((size_t)(b * NN + n)) * T1C + t) * HHC;
    h[obase + lane] = v0;
    h[obase + lane + 64] = v1;
    hb[obase + lane] = f2b(v0);
    hb[obase + lane + 64] = f2b(v1);
}

// ---------------- graph attention ----------------

__global__ __launch_bounds__(256) void emea_k(const float* __restrict__ e, const int* __restrict__ epos,
                                              const float* __restrict__ Wem, const float* __restrict__ bem,
                                              const float* __restrict__ Wea, const float* __restrict__ bea,
                                              float* __restrict__ emp1c, float* __restrict__ eawc)
{
    int r = blockIdx.x * blockDim.x + threadIdx.x;
    if (r >= EEC) return;
    float ev[DEC];
#pragma unroll
    for (int k = 0; k < DEC; k++) ev[k] = e[r * DEC + k];
    int pos = epos[r];
#pragma unroll
    for (int hh = 0; hh < NHD; hh++) {
        float a = bem[hh], b2 = bea[hh];
#pragma unroll
        for (int k = 0; k < DEC; k++) { a += ev[k] * Wem[k * NHD + hh]; b2 += ev[k] * Wea[k * NHD + hh]; }
        emp1c[pos * NHD + hh] = a + 1.f;
        eawc[pos * NHD + hh] = b2;
    }
}

// w = exp(score) in CSR order; 2 edges per iteration for MLP
__global__ __launch_bounds__(128) void score_k(const unsigned short* __restrict__ Q,
                                               const unsigned short* __restrict__ K,
                                               const int* __restrict__ dstCSR, const int* __restrict__ srcCSR,
                                               const float* __restrict__ emp1c, const float* __restrict__ eawc,
                                               float* __restrict__ w)
{
    int bt = blockIdx.y;
    int tid = threadIdx.x;
    int hh = tid & 3, isub = tid >> 2;
    size_t base = (size_t)bt * NN;
    int stride = gridDim.x * 32;
    for (int i = blockIdx.x * 32 + isub; i < EEC; i += 2 * stride) {
        int j = i + stride;
        bool hasj = j < EEC;
        int dn0 = dstCSR[i], sn0 = srcCSR[i];
        int dn1 = hasj ? dstCSR[j] : dn0;
        int sn1 = hasj ? srcCSR[j] : sn0;
        const uint4* q0 = (const uint4*)(Q + (base + dn0) * HHC + hh * 32);
        const uint4* k0 = (const uint4*)(K + (base + sn0) * HHC + hh * 32);
        const uint4* q1 = (const uint4*)(Q + (base + dn1) * HHC + hh * 32);
        const uint4* k1 = (const uint4*)(K + (base + sn1) * HHC + hh * 32);
        float acc0 = 0.f, acc1 = 0.f;
#pragma unroll
        for (int d = 0; d < 4; d++) {
            uint4 a0 = q0[d], b0 = k0[d], a1 = q1[d], b1 = k1[d];
            unsigned av0[4] = {a0.x, a0.y, a0.z, a0.w};
            unsigned bv0[4] = {b0.x, b0.y, b0.z, b0.w};
            unsigned av1[4] = {a1.x, a1.y, a1.z, a1.w};
            unsigned bv1[4] = {b1.x, b1.y, b1.z, b1.w};
#pragma unroll
            for (int jj = 0; jj < 4; jj++) {
                acc0 += __uint_as_float(av0[jj] << 16) * __uint_as_float(bv0[jj] << 16);
                acc0 += __uint_as_float(av0[jj] & 0xFFFF0000u) * __uint_as_float(bv0[jj] & 0xFFFF0000u);
                acc1 += __uint_as_float(av1[jj] << 16) * __uint_as_float(bv1[jj] << 16);
                acc1 += __uint_as_float(av1[jj] & 0xFFFF0000u) * __uint_as_float(bv1[jj] & 0xFFFF0000u);
            }
        }
        float sc0 = acc0 * SCALEQK * emp1c[i * NHD + hh] + eawc[i * NHD + hh];
        w[((size_t)bt * EEC + i) * NHD + hh] = expf(sc0);
        if (hasj) {
            float sc1 = acc1 * SCALEQK * emp1c[j * NHD + hh] + eawc[j * NHD + hh];
            w[((size_t)bt * EEC + j) * NHD + hh] = expf(sc1);
        }
    }
}

// weighted gather-sum over CSR; 4-wide unroll for MLP
__global__ __launch_bounds__(128) void agg_k(const unsigned short* __restrict__ V,
                                             const int* __restrict__ rowptr, const int* __restrict__ srcCSR,
                                             const float* __restrict__ w, unsigned short* __restrict__ outb)
{
    int blk = blockIdx.x;
    int bt = blk / NN, n = blk - bt * NN;
    int tid = threadIdx.x;
    int hh = tid >> 5, lane = tid & 31;
    size_t base = (size_t)bt * NN;
    int oc = hh * 32 + lane;
    const float* wp = w + (size_t)bt * EEC * NHD + hh;
    float den = 0.f, acc = 0.f;
    int s0 = rowptr[n], s1 = rowptr[n + 1];
    int i = s0;
    for (; i + 3 < s1; i += 4) {
        int sn0 = srcCSR[i], sn1 = srcCSR[i + 1], sn2 = srcCSR[i + 2], sn3 = srcCSR[i + 3];
        float w0 = wp[(size_t)i * NHD];
        float w1 = wp[(size_t)(i + 1) * NHD];
        float w2 = wp[(size_t)(i + 2) * NHD];
        float w3 = wp[(size_t)(i + 3) * NHD];
        float v0 = b2f(V[(base + sn0) * HHC + oc]);
        float v1 = b2f(V[(base + sn1) * HHC + oc]);
        float v2 = b2f(V[(base + sn2) * HHC + oc]);
        float v3 = b2f(V[(base + sn3) * HHC + oc]);
        acc += w0 * v0 + w1 * v1 + w2 * v2 + w3 * v3;
        den += (w0 + w1) + (w2 + w3);
    }
    for (; i < s1; i++) {
        int sn = srcCSR[i];
        float wv = wp[(size_t)i * NHD];
        acc += wv * b2f(V[(base + sn) * HHC + oc]);
        den += wv;
    }
    outb[(base + n) * HHC + oc] = f2b(acc / (den + 1e-9f));
}

__global__ __launch_bounds__(128) void hmean_k(const float* __restrict__ hBT, float* __restrict__ hmean)
{
    int n = blockIdx.x, c = threadIdx.x;
    float s = 0.f;
#pragma unroll
    for (int bt = 0; bt < BTC; bt++) s += hBT[((size_t)bt * NN + n) * HHC + c];
    hmean[n * HHC + c] = s * (1.f / BTC);
}

__global__ __launch_bounds__(256) void ein_k(const float* __restrict__ hmean, const int* __restrict__ dst,
                                             const int* __restrict__ src, const float* __restrict__ e,
                                             unsigned short* __restrict__ einb)
{
    int i = blockIdx.x * blockDim.x + threadIdx.x;
    if (i >= EEC * 288) return;
    int r = i / 288, j = i - r * 288;
    float v;
    if (j < HHC) v = hmean[dst[r] * HHC + j];
    else if (j < 2 * HHC) v = hmean[src[r] * HHC + (j - HHC)];
    else if (j < 2 * HHC + DEC) v = e[r * DEC + (j - 2 * HHC)];
    else v = 0.f;
    einb[i] = f2b(v);
}

__global__ __launch_bounds__(256) void eln_k(float* __restrict__ e, const float* __restrict__ emlp,
                                             const float* __restrict__ g, const float* __restrict__ be)
{
    int r = blockIdx.x * blockDim.x + threadIdx.x;
    if (r >= EEC) return;
    float x[DEC];
    float s = 0.f;
#pragma unroll
    for (int c = 0; c < DEC; c++) { x[c] = e[r * DEC + c] + emlp[r * DEC + c]; s += x[c]; }
    float m = s * (1.f / DEC);
    float v = 0.f;
#pragma unroll
    for (int c = 0; c < DEC; c++) { float d = x[c] - m; v += d * d; }
    v *= (1.f / DEC);
    float rstd = rsqrtf(v + EPSLN);
#pragma unroll
    for (int c = 0; c < DEC; c++) e[r * DEC + c] = (x[c] - m) * rstd * g[c] + be[c];
}

// ---------------- output head: one wave per row ----------------

__global__ __launch_bounds__(256) void out_k(const float* __restrict__ h, const float* __restrict__ Wout,
                                             const float* __restrict__ bout, float* __restrict__ out)
{
    int row = blockIdx.x * 4 + (threadIdx.x >> 6);
    int lane = threadIdx.x & 63;
    const float* hp = h + (size_t)row * HHC;
    float x0 = hp[lane], x1 = hp[lane + 64];
    float w00 = Wout[lane * 4 + 0], w01 = Wout[lane * 4 + 1];
    float w02 = Wout[lane * 4 + 2], w03 = Wout[lane * 4 + 3];
    float w10 = Wout[(lane + 64) * 4 + 0], w11 = Wout[(lane + 64) * 4 + 1];
    float w12 = Wout[(lane + 64) * 4 + 2], w13 = Wout[(lane + 64) * 4 + 3];
    float p0 = x0 * w00 + x1 * w10;
    float p1 = x0 * w01 + x1 * w11;
    float p2 = x0 * w02 + x1 * w12;
    float p3 = x0 * w03 + x1 * w13;
#pragma unroll
    for (int m = 32; m >= 1; m >>= 1) {
        p0 += __shfl_xor(p0, m, 64);
        p1 += __shfl_xor(p1, m, 64);
        p2 += __shfl_xor(p2, m, 64);
        p3 += __shfl_xor(p3, m, 64);
    }
    if (lane == 0) {
        float l0 = p0 + bout[0], l1 = p1 + bout[1], l2 = p2 + bout[2], l3 = p3 + bout[3];
        float mx = fmaxf(fmaxf(l0, l1), fmaxf(l2, l3));
        float e0 = expf(l0 - mx), e1 = expf(l1 - mx), e2 = expf(l2 - mx), e3 = expf(l3 - mx);
        float inv = 1.f / (e0 + e1 + e2 + e3);
        float4 o = {e0 * inv, e1 * inv, e2 * inv, e3 * inv};
        *(float4*)(out + (size_t)row * 4) = o;
    }
}

// ---------------- launch ----------------

extern "C" void kernel_launch(void* const* d_in, const int* in_sizes, int n_in,
                              void* d_out, int out_size, void* d_ws, size_t ws_size,
                              hipStream_t stream)
{
    const float* Xk      = (const float*)d_in[0];
    const float* temb    = (const float*)d_in[1];
    const float* stepemb = (const float*)d_in[2];
    const float* Wtr     = (const float*)d_in[3];
    const float* btr     = (const float*)d_in[4];
    const float* Win     = (const float*)d_in[5];
    const float* bin     = (const float*)d_in[6];
    const float* gin     = (const float*)d_in[7];
    const float* bein    = (const float*)d_in[8];
    const float* We      = (const float*)d_in[9];
    const float* bE      = (const float*)d_in[10];
    const float* aw      = (const float*)d_in[11];
    const float* ab      = (const float*)d_in[12];
    const float* ow      = (const float*)d_in[13];
    const float* ob      = (const float*)d_in[14];
    const float* tng     = (const float*)d_in[15];
    const float* tnb     = (const float*)d_in[16];
    const float* f1w     = (const float*)d_in[17];
    const float* f1b     = (const float*)d_in[18];
    const float* f2w     = (const float*)d_in[19];
    const float* f2b_    = (const float*)d_in[20];
    const float* fng     = (const float*)d_in[21];
    const float* fnb     = (const float*)d_in[22];
    const float* Wq      = (const float*)d_in[23];
    const float* Wk      = (const float*)d_in[24];
    const float* Wv      = (const float*)d_in[25];
    const float* Wo      = (const float*)d_in[26];
    const float* bo      = (const float*)d_in[27];
    const float* Wem     = (const float*)d_in[28];
    const float* bem     = (const float*)d_in[29];
    const float* Wea     = (const float*)d_in[30];
    const float* bea     = (const float*)d_in[31];
    const float* e1w     = (const float*)d_in[32];
    const float* e1b     = (const float*)d_in[33];
    const float* e2w     = (const float*)d_in[34];
    const float* e2b     = (const float*)d_in[35];
    const float* gng     = (const float*)d_in[36];
    const float* gnb     = (const float*)d_in[37];
    const float* eng     = (const float*)d_in[38];
    const float* enb     = (const float*)d_in[39];
    const float* Wout    = (const float*)d_in[40];
    const float* bout    = (const float*)d_in[41];
    const int*   kidx    = (const int*)d_in[42];
    const int*   eidx    = (const int*)d_in[43];
    float* outp = (float*)d_out;

    char* wsp = (char*)d_ws;
    auto alloc = [&](size_t nbytes) -> void* {
        void* p = (void*)wsp;
        wsp += (nbytes + 255) & ~(size_t)255;
        return p;
    };
    float* h     = (float*)alloc((size_t)MROWS * HHC * 4);
    unsigned short* hb = (unsigned short*)alloc((size_t)MROWS * HHC * 2);
    float* hBT   = (float*)alloc((size_t)MROWS * HHC * 4);
    unsigned short* hBTb = (unsigned short*)alloc((size_t)MROWS * HHC * 2);
    float* bufC  = (float*)alloc((size_t)MROWS * 384 * 4);
    unsigned short* bufDb = (unsigned short*)alloc((size_t)MROWS * HHC * 2);
    float* ebuf  = (float*)alloc((size_t)EEC * DEC * 4);
    float* emp1c = (float*)alloc((size_t)EEC * NHD * 4);
    float* eawc  = (float*)alloc((size_t)EEC * NHD * 4);
    float* emid  = (float*)alloc((size_t)EEC * 64 * 4);
    float* emlp  = (float*)alloc((size_t)EEC * DEC * 4);
    float* hmean = (float*)alloc((size_t)NN * HHC * 4);
    float* tre   = (float*)alloc((size_t)T1C * HHC * 4);
    float* wbuf  = (float*)alloc((size_t)BTC * EEC * NHD * 4);
    float* degmaxf = (float*)alloc(4);
    int* degi   = (int*)alloc((size_t)NN * 4);
    int* dst    = (int*)alloc((size_t)EEC * 4);
    int* srcA   = (int*)alloc((size_t)EEC * 4);
    int* srcCSR = (int*)alloc((size_t)EEC * 4);
    int* dstCSR = (int*)alloc((size_t)EEC * 4);
    int* epos   = (int*)alloc((size_t)EEC * 4);
    int* rowptr = (int*)alloc((size_t)(NN + 1) * 4);
    int* cursor = (int*)alloc((size_t)NN * 4);
    unsigned short* awP   = (unsigned short*)alloc((size_t)LLC * 384 * 128 * 2);
    unsigned short* owP   = (unsigned short*)alloc((size_t)LLC * 128 * 128 * 2);
    unsigned short* f1P   = (unsigned short*)alloc((size_t)LLC * 256 * 128 * 2);
    unsigned short* f2P   = (unsigned short*)alloc((size_t)LLC * 128 * 256 * 2);
    unsigned short* WqkvP = (unsigned short*)alloc((size_t)LLC * 384 * 128 * 2);
    unsigned short* WoP   = (unsigned short*)alloc((size_t)LLC * 128 * 128 * 2);
    unsigned short* e1T   = (unsigned short*)alloc((size_t)LLC * 64 * 288 * 2);

    unsigned short* bufCb = (unsigned short*)bufC;
    unsigned short* midb  = (unsigned short*)bufC;
    unsigned short* Qc    = (unsigned short*)bufC;
    unsigned short* Kc    = Qc + (size_t)MROWS * HHC;
    unsigned short* Vc    = Kc + (size_t)MROWS * HHC;
    unsigned short* einb  = (unsigned short*)bufC;

    {
        auto cwp = [&](const float* W, unsigned short* Bp, int K, int N, int noff, int Ntot) {
            int total = LLC * K * N;
            convwp_k<<<(total + 255) / 256, 256, 0, stream>>>(W, Bp, LLC, K, N, noff, Ntot);
        };
        cwp(aw,  awP, 128, 384, 0, 384);
        cwp(ow,  owP, 128, 128, 0, 128);
        cwp(f1w, f1P, 128, 256, 0, 256);
        cwp(f2w, f2P, 256, 128, 0, 128);
        cwp(Wq,  WqkvP, 128, 128, 0,   384);
        cwp(Wk,  WqkvP, 128, 128, 128, 384);
        cwp(Wv,  WqkvP, 128, 128, 256, 384);
        cwp(Wo,  WoP, 128, 128, 0, 128);
        int totalE1 = LLC * 64 * 288;
        convw_k<<<(totalE1 + 255) / 256, 256, 0, stream>>>(e1w, e1T, LLC, 272, 64, 288, 64 * 288, 0);
    }

    zero_deg_k<<<(NN + 255) / 256, 256, 0, stream>>>(degi);
    build_edges_k<<<(EEC + 255) / 256, 256, 0, stream>>>(eidx, dst, srcA, degi);
    scan_k<<<1, 256, 0, stream>>>(degi, rowptr, cursor, degmaxf);
    feat_k<<<(EEC + 255) / 256, 256, 0, stream>>>(dst, srcA, degi, degmaxf, cursor, srcCSR, dstCSR, epos, We, bE, ebuf);

    embed_k<<<MROWS, 128, 0, stream>>>(Xk, temb, Win, bin, gin, bein, stepemb, kidx, h, hb);
    tre_k<<<T1C, 128, 0, stream>>>(temb, Wtr, btr, tre);

    for (int l = 0; l < LLC; l++) {
        const unsigned short* awP_l   = awP   + (size_t)l * 384 * 128;
        const unsigned short* owP_l   = owP   + (size_t)l * 128 * 128;
        const unsigned short* f1P_l   = f1P   + (size_t)l * 256 * 128;
        const unsigned short* f2P_l   = f2P   + (size_t)l * 128 * 256;
        const unsigned short* WqkvP_l = WqkvP + (size_t)l * 384 * 128;
        const unsigned short* WoP_l   = WoP   + (size_t)l * 128 * 128;
        const unsigned short* e1T_l   = e1T   + (size_t)l * 64 * 288;
        const float* ab_l  = ab  + (size_t)l * 3 * HHC;
        const float* ob_l  = ob  + (size_t)l * HHC;
        const float* tng_l = tng + (size_t)l * HHC;
        const float* tnb_l = tnb + (size_t)l * HHC;
        const float* f1b_l = f1b + (size_t)l * 256;
        const float* f2b_l = f2b_ + (size_t)l * HHC;
        const float* fng_l = fng + (size_t)l * HHC;
        const float* fnb_l = fnb + (size_t)l * HHC;
        const float* bo_l  = bo  + (size_t)l * HHC;
        const float* Wem_l = Wem + (size_t)l * DEC * NHD;
        const float* bem_l = bem + (size_t)l * NHD;
        const float* Wea_l = Wea + (size_t)l * DEC * NHD;
        const float* bea_l = bea + (size_t)l * NHD;
        const float* e1b_l = e1b + (size_t)l * 64;
        const float* e2w_l = e2w + (size_t)l * 64 * DEC;
        const float* e2b_l = e2b + (size_t)l * DEC;
        const float* gng_l = gng + (size_t)l * HHC;
        const float* gnb_l = gnb + (size_t)l * HHC;
        const float* eng_l = eng + (size_t)l * DEC;
        const float* enb_l = enb + (size_t)l * DEC;

        // temporal attention (qkv in bf16)
        run_gemm2<128, 0, 2>(hb, awP_l, ab_l, nullptr, bufCb, nullptr, nullptr, nullptr, MROWS, 384, stream);
        temporal_attn_k<<<BBC * NN, 128, 0, stream>>>(bufCb, bufDb);
        run_gemm2<128, 3, 3>(bufDb, owP_l, ob_l, h, hb, h, tng_l, tnb_l, MROWS, 128, stream);
        // FFN
        run_gemm2<128, 1, 2>(hb, f1P_l, f1b_l, nullptr, midb, nullptr, nullptr, nullptr, MROWS, 256, stream);
        run_gemm2<256, 3, 1>(midb, f2P_l, f2b_l, h, nullptr, h, fng_l, fnb_l, MROWS, 128, stream);
        // + t_re, transpose to [BT, N, H]
        addtre_T_k<<<(MROWS * HHC + 255) / 256, 256, 0, stream>>>(h, tre, hBT, hBTb);
        // graph attention: fused QKV GEMM, split compact outputs
        run_gemm2<128, 0, 4>(hBTb, WqkvP_l, nullptr, nullptr, Qc, nullptr, nullptr, nullptr, MROWS, 384, stream);
        emea_k<<<(EEC + 255) / 256, 256, 0, stream>>>(ebuf, epos, Wem_l, bem_l, Wea_l, bea_l, emp1c, eawc);
        score_k<<<dim3(64, BTC), 128, 0, stream>>>(Qc, Kc, dstCSR, srcCSR, emp1c, eawc, wbuf);
        agg_k<<<BTC * NN, 128, 0, stream>>>(Vc, rowptr, srcCSR, wbuf, bufDb);
        run_gemm2<128, 2, 1>(bufDb, WoP_l, bo_l, hBT, nullptr, hBT, nullptr, nullptr, MROWS, 128, stream);
        // edge update
        hmean_k<<<NN, 128, 0, stream>>>(hBT, hmean);
        ein_k<<<(EEC * 288 + 255) / 256, 256, 0, stream>>>(hmean, dst, srcA, ebuf, einb);
        gemm_mfma_k<2, 1, 1><<<(EEC + 31) / 32, 256, 0, stream>>>(einb, e1T_l, e1b_l, emid, nullptr,
                                                                  nullptr, nullptr, nullptr, EEC, 288);
        gemm_k<0, 64><<<(EEC + 15) / 16, 128, 0, stream>>>(emid, e2w_l, e2b_l, emlp, EEC, DEC);
        eln_k<<<(EEC + 255) / 256, 256, 0, stream>>>(ebuf, emlp, eng_l, enb_l);
        // final LN + transpose back to [B,N,T1,H] (wave-per-row)
        lnT_k<<<MROWS / 4, 256, 0, stream>>>(hBT, gng_l, gnb_l, h, hb);
    }

    out_k<<<MROWS / 4, 256, 0, stream>>>(h, Wout, bout, outp);
}

// Round 17
// 1370.353 us; speedup vs baseline: 1.2087x; 1.0111x over previous
//
#include <hip/hip_runtime.h>
#include <math.h>

#define NN 2000
#define T1C 12
#define BBC 2
#define HHC 128
#define NHD 4
#define DFD 32
#define LLC 4
#define DEC 16
#define TEC 16
#define CINC 12
#define E0C 32000
#define EEC 34000
#define BTC 24
#define MROWS 48000
#define EPSLN 1e-5f
#define SCALEQK 0.17677669529663687f

typedef __attribute__((ext_vector_type(8))) short short8;
typedef __attribute__((ext_vector_type(4))) float f32x4;

// ---------------- helpers ----------------

__device__ __forceinline__ unsigned short f2b(float f)
{
    unsigned u = __float_as_uint(f);
    return (unsigned short)((u + 0x7FFF + ((u >> 16) & 1)) >> 16);
}

__device__ __forceinline__ float b2f(unsigned short h)
{
    return __uint_as_float(((unsigned)h) << 16);
}

__device__ __forceinline__ float blockSum128(float v, volatile float* s2)
{
    for (int m = 32; m >= 1; m >>= 1) v += __shfl_xor(v, m, 64);
    int w = threadIdx.x >> 6;
    __syncthreads();
    if ((threadIdx.x & 63) == 0) s2[w] = v;
    __syncthreads();
    return s2[0] + s2[1];
}

// ---------------- weight conversions ----------------

__global__ __launch_bounds__(256) void convw_k(const float* __restrict__ W, unsigned short* __restrict__ WT,
                                               int LN_, int K, int N, int Kp, int ostride, int ooff)
{
    int idx = blockIdx.x * blockDim.x + threadIdx.x;
    int total = LN_ * N * Kp;
    if (idx >= total) return;
    int l = idx / (N * Kp);
    int r = idx - l * (N * Kp);
    int n = r / Kp;
    int k = r - n * Kp;
    WT[(size_t)l * ostride + (size_t)(ooff + n) * Kp + k] =
        (k < K) ? f2b(W[(size_t)l * K * N + (size_t)k * N + n]) : 0;
}

__global__ __launch_bounds__(256) void convwp_k(const float* __restrict__ W, unsigned short* __restrict__ Bp,
                                                int LN_, int K, int N, int noff, int Ntot)
{
    int idx = blockIdx.x * blockDim.x + threadIdx.x;
    int total = LN_ * K * N;
    if (idx >= total) return;
    int l = idx / (K * N);
    int r = idx - l * (K * N);
    int k = r / N;
    int n = r - k * N + noff;
    size_t off = (size_t)l * K * Ntot +
                 ((size_t)((n >> 4) * (K >> 5) + (k >> 5)) << 9) +
                 (((k >> 3) & 3) << 7) + ((n & 15) << 3) + (k & 7);
    Bp[off] = f2b(W[idx]);
}

// ---------------- gemm2: 128x128-tile LDS-staged MFMA GEMM ----------------

template<int K, int EPI, int OUTM>
__global__ __launch_bounds__(256) void gemm2_k(
    const unsigned short* __restrict__ A, const unsigned short* __restrict__ Bp,
    const float* __restrict__ bias, float* __restrict__ C, unsigned short* __restrict__ Cb,
    const float* __restrict__ res, const float* __restrict__ gam, const float* __restrict__ bet,
    int M, int Ntot)
{
    __shared__ unsigned short A_s[128 * 16 * 8];
    __shared__ float red2[2][128][2];

    int tid = threadIdx.x;
    int w = tid >> 6, lane = tid & 63;
    int wr = w & 1, wc = w >> 1;
    int quad = lane >> 4, lr = lane & 15;

    const unsigned short* abase = A + (size_t)blockIdx.x * 128 * K;
    int ntg0 = blockIdx.y * 8 + wc * 4;

    f32x4 acc[4][4];
#pragma unroll
    for (int mt = 0; mt < 4; mt++)
#pragma unroll
        for (int nt = 0; nt < 4; nt++) acc[mt][nt] = (f32x4){0.f, 0.f, 0.f, 0.f};

#pragma unroll
    for (int kb = 0; kb < K; kb += 128) {
        if (kb) __syncthreads();
#pragma unroll
        for (int j = 0; j < 8; j++) {
            int s = j * 256 + tid;
            int row = s >> 4, ks = s & 15;
            int ko = ks ^ (row & 15);
            uint4 d = *(const uint4*)(abase + (size_t)row * K + kb + ko * 8);
            *(uint4*)(A_s + s * 8) = d;
        }
        __syncthreads();
#pragma unroll
        for (int k0 = 0; k0 < 128; k0 += 32) {
            short8 af[4], bf[4];
#pragma unroll
            for (int mt = 0; mt < 4; mt++) {
                int row_l = wr * 64 + mt * 16 + lr;
                int koct = (k0 >> 3) + quad;
                int slot = row_l * 16 + (koct ^ lr);
                af[mt] = *(const short8*)(A_s + slot * 8);
            }
#pragma unroll
            for (int nt = 0; nt < 4; nt++) {
                size_t off = ((size_t)(ntg0 + nt) * (K >> 5) + ((kb + k0) >> 5)) * 512 + lane * 8;
                bf[nt] = *(const short8*)(Bp + off);
            }
#pragma unroll
            for (int mt = 0; mt < 4; mt++)
#pragma unroll
                for (int nt = 0; nt < 4; nt++)
                    acc[mt][nt] = __builtin_amdgcn_mfma_f32_16x16x32_bf16(af[mt], bf[nt], acc[mt][nt], 0, 0, 0);
        }
    }

    int rbase = blockIdx.x * 128 + wr * 64;
    int cbase = blockIdx.y * 128 + wc * 64;

    if constexpr (EPI != 3) {
#pragma unroll
        for (int mt = 0; mt < 4; mt++) {
#pragma unroll
            for (int nt = 0; nt < 4; nt++) {
                int colg = cbase + nt * 16 + lr;
                float bv = bias ? bias[colg] : 0.f;
#pragma unroll
                for (int i = 0; i < 4; i++) {
                    int row = rbase + mt * 16 + quad * 4 + i;
                    float x = acc[mt][nt][i] + bv;
                    if constexpr (EPI == 1) x = 0.5f * x * (1.f + erff(x * 0.70710678118654752f));
                    if constexpr (EPI == 2) x = res[(size_t)row * Ntot + colg] + x;
                    if constexpr (OUTM & 1) C[(size_t)row * Ntot + colg] = x;
                    if constexpr (OUTM & 4)
                        Cb[(size_t)blockIdx.y * M * 128 + (size_t)row * 128 + (wc * 64 + nt * 16 + lr)] = f2b(x);
                    else if constexpr (OUTM & 2)
                        Cb[(size_t)row * Ntot + colg] = f2b(x);
                }
            }
        }
    } else {
        float s[4][4], s2l[4][4];
#pragma unroll
        for (int mt = 0; mt < 4; mt++)
#pragma unroll
            for (int i = 0; i < 4; i++) { s[mt][i] = 0.f; s2l[mt][i] = 0.f; }
#pragma unroll
        for (int mt = 0; mt < 4; mt++) {
#pragma unroll
            for (int nt = 0; nt < 4; nt++) {
                int colg = cbase + nt * 16 + lr;
                float bv = bias[colg];
#pragma unroll
                for (int i = 0; i < 4; i++) {
                    int row = rbase + mt * 16 + quad * 4 + i;
                    float x = acc[mt][nt][i] + bv + res[(size_t)row * 128 + colg];
                    acc[mt][nt][i] = x;
                    s[mt][i] += x;
                    s2l[mt][i] += x * x;
                }
            }
        }
#pragma unroll
        for (int m = 1; m < 16; m <<= 1) {
#pragma unroll
            for (int mt = 0; mt < 4; mt++)
#pragma unroll
                for (int i = 0; i < 4; i++) {
                    s[mt][i]  += __shfl_xor(s[mt][i], m, 64);
                    s2l[mt][i] += __shfl_xor(s2l[mt][i], m, 64);
                }
        }
        if (lr == 0) {
#pragma unroll
            for (int mt = 0; mt < 4; mt++)
#pragma unroll
                for (int i = 0; i < 4; i++) {
                    int rl = wr * 64 + mt * 16 + quad * 4 + i;
                    red2[wc][rl][0] = s[mt][i];
                    red2[wc][rl][1] = s2l[mt][i];
                }
        }
        __syncthreads();
#pragma unroll
        for (int mt = 0; mt < 4; mt++) {
#pragma unroll
            for (int i = 0; i < 4; i++) {
                int rl = wr * 64 + mt * 16 + quad * 4 + i;
                float st  = red2[0][rl][0] + red2[1][rl][0];
                float s2t = red2[0][rl][1] + red2[1][rl][1];
                float mu = st * (1.f / 128.f);
                float rstd = rsqrtf(s2t * (1.f / 128.f) - mu * mu + EPSLN);
                int row = rbase + mt * 16 + quad * 4 + i;
#pragma unroll
                for (int nt = 0; nt < 4; nt++) {
                    int colg = cbase + nt * 16 + lr;
                    float y = (acc[mt][nt][i] - mu) * rstd * gam[colg] + bet[colg];
                    if constexpr (OUTM & 1) C[(size_t)row * 128 + colg] = y;
                    if constexpr (OUTM & 2) Cb[(size_t)row * 128 + colg] = f2b(y);
                }
            }
        }
    }
}

template<int K, int EPI, int OUTM>
static void run_gemm2(const unsigned short* A, const unsigned short* Bp, const float* bias,
                      float* C, unsigned short* Cb, const float* res, const float* g, const float* be,
                      int M, int Ntot, hipStream_t stream)
{
    dim3 grid(M / 128, Ntot / 128);
    gemm2_k<K, EPI, OUTM><<<grid, 256, 0, stream>>>(A, Bp, bias, C, Cb, res, g, be, M, Ntot);
}

// ---------------- old-style MFMA GEMM (e1: K=288, N=64, M=34000) ----------------

template<int NT, int EPI, int OUTM>
__global__ __launch_bounds__(256) void gemm_mfma_k(
    const unsigned short* __restrict__ A, const unsigned short* __restrict__ WT,
    const float* __restrict__ bias, float* __restrict__ C, unsigned short* __restrict__ Cb,
    const float* __restrict__ res, const float* __restrict__ gam, const float* __restrict__ bet,
    int M, int K)
{
    const int Nc = NT * 32;
    int tid = threadIdx.x;
    int w = tid >> 6, lane = tid & 63;
    int wr = w & 1, wc = w >> 1;
    int r0 = blockIdx.x * 32 + wr * 16;
    int c0 = wc * NT * 16;
    int lr = lane & 15;
    int kq = (lane >> 4) * 8;
    int arow = r0 + lr; if (arow >= M) arow = M - 1;
    const unsigned short* ap = A + (size_t)arow * K + kq;
    const unsigned short* wp = WT + (size_t)(c0 + lr) * K + kq;

    f32x4 acc[NT];
#pragma unroll
    for (int t = 0; t < NT; t++) acc[t] = (f32x4){0.f, 0.f, 0.f, 0.f};

    for (int k0 = 0; k0 < K; k0 += 32) {
        short8 a = *(const short8*)(ap + k0);
#pragma unroll
        for (int t = 0; t < NT; t++) {
            short8 b = *(const short8*)(wp + (size_t)t * 16 * K + k0);
            acc[t] = __builtin_amdgcn_mfma_f32_16x16x32_bf16(a, b, acc[t], 0, 0, 0);
        }
    }

    int orow0 = r0 + (lane >> 4) * 4;
#pragma unroll
    for (int t = 0; t < NT; t++) {
        int col = c0 + t * 16 + lr;
        float bv = bias ? bias[col] : 0.f;
#pragma unroll
        for (int i = 0; i < 4; i++) {
            int row = orow0 + i;
            if (row < M) {
                float x = acc[t][i] + bv;
                if constexpr (EPI == 1) x = 0.5f * x * (1.f + erff(x * 0.70710678118654752f));
                if constexpr (EPI == 2) x = res[(size_t)row * Nc + col] + x;
                if constexpr (OUTM & 1) C[(size_t)row * Nc + col] = x;
                if constexpr (OUTM & 2) Cb[(size_t)row * Nc + col] = f2b(x);
            }
        }
    }
}

// ---------------- fp32 fallback GEMM (small: e2) ----------------

template<int EPI, int K>
__global__ __launch_bounds__(128) void gemm_k(
    const float* __restrict__ A, const float* __restrict__ W,
    const float* __restrict__ bias, float* __restrict__ C,
    int M, int Nc)
{
    __shared__ float As[16 * K];
    int tid = threadIdx.x;
    int row0 = blockIdx.x * 16;
    for (int i = tid; i < 16 * K; i += 128) {
        int r = i / K, k = i - r * K;
        int row = row0 + r;
        As[i] = (row < M) ? A[(size_t)row * K + k] : 0.f;
    }
    __syncthreads();
    for (int c = tid; c < Nc; c += 128) {
        float acc[16];
#pragma unroll
        for (int r = 0; r < 16; r++) acc[r] = 0.f;
        const float* wp = W + c;
        for (int k = 0; k < K; k++) {
            float w = wp[(size_t)k * Nc];
#pragma unroll
            for (int r = 0; r < 16; r++) acc[r] += As[r * K + k] * w;
        }
        float bv = bias ? bias[c] : 0.f;
#pragma unroll
        for (int r = 0; r < 16; r++) {
            int row = row0 + r;
            if (row < M) C[(size_t)row * Nc + c] = acc[r] + bv;
        }
    }
}

// ---------------- graph precompute ----------------

__global__ __launch_bounds__(256) void zero_deg_k(int* __restrict__ degi)
{
    int i = blockIdx.x * blockDim.x + threadIdx.x;
    if (i < NN) degi[i] = 0;
}

__global__ __launch_bounds__(256) void build_edges_k(const int* __restrict__ eidx,
                                                     int* __restrict__ dst, int* __restrict__ src,
                                                     int* __restrict__ degi)
{
    int e = blockIdx.x * blockDim.x + threadIdx.x;
    if (e >= EEC) return;
    int d, s;
    if (e < E0C) { d = eidx[e]; s = eidx[E0C + e]; }
    else { d = e - E0C; s = e - E0C; }
    dst[e] = d;
    src[e] = s;
    atomicAdd(&degi[d], 1);
}

__global__ __launch_bounds__(256) void scan_k(const int* __restrict__ degi, int* __restrict__ rowptr,
                                              int* __restrict__ cursor, float* __restrict__ degmaxf)
{
    __shared__ int ssum[256];
    __shared__ int smx[256];
    int tid = threadIdx.x;
    int vals[8];
    int s = 0, mx = 0;
    int base = tid * 8;
#pragma unroll
    for (int j = 0; j < 8; j++) {
        int idx = base + j;
        int v = (idx < NN) ? degi[idx] : 0;
        vals[j] = v; s += v; mx = max(mx, v);
    }
    ssum[tid] = s; smx[tid] = mx;
    __syncthreads();
    for (int off = 1; off < 256; off <<= 1) {
        int t = (tid >= off) ? ssum[tid - off] : 0;
        __syncthreads();
        ssum[tid] += t;
        __syncthreads();
    }
    for (int off = 128; off > 0; off >>= 1) {
        if (tid < off) smx[tid] = max(smx[tid], smx[tid + off]);
        __syncthreads();
    }
    if (tid == 0) *degmaxf = fmaxf((float)smx[0], 1.f);
    int running = ssum[tid] - s;
#pragma unroll
    for (int j = 0; j < 8; j++) {
        int idx = base + j;
        if (idx < NN) { rowptr[idx] = running; cursor[idx] = running; running += vals[j]; }
    }
    if (tid == 255) rowptr[NN] = ssum[255];
}

__global__ __launch_bounds__(256) void feat_k(const int* __restrict__ dst, const int* __restrict__ src,
                                              const int* __restrict__ degi, const float* __restrict__ degmaxf,
                                              int* __restrict__ cursor, int* __restrict__ srcCSR,
                                              int* __restrict__ dstCSR, int* __restrict__ epos,
                                              const float* __restrict__ We, const float* __restrict__ bE,
                                              float* __restrict__ e)
{
    int ei = blockIdx.x * blockDim.x + threadIdx.x;
    if (ei >= EEC) return;
    int d = dst[ei], s = src[ei];
    int pos = atomicAdd(&cursor[d], 1);
    srcCSR[pos] = s;
    dstCSR[pos] = d;
    epos[ei] = pos;
    float dm = *degmaxf;
    float degd = (float)degi[d], degs = (float)degi[s];
    float f0 = 1.f / fmaxf(degd, 1.f);
    float f1 = degs / dm, f2 = degd / dm;
#pragma unroll
    for (int c = 0; c < DEC; c++)
        e[ei * DEC + c] = bE[c] + f0 * We[c] + f1 * We[DEC + c] + f2 * We[2 * DEC + c];
}

// ---------------- embedding ----------------

__global__ __launch_bounds__(128) void embed_k(const float* __restrict__ Xk, const float* __restrict__ temb,
                                               const float* __restrict__ Win, const float* __restrict__ bin,
                                               const float* __restrict__ g, const float* __restrict__ be,
                                               const float* __restrict__ stepemb, const int* __restrict__ kidx,
                                               float* __restrict__ h, unsigned short* __restrict__ hb)
{
    int row = blockIdx.x;
    int t = row % T1C;
    int bn = row / T1C;
    int b = bn / NN;
    __shared__ float x[28];
    __shared__ float s2[2];
    int tid = threadIdx.x;
    if (tid < CINC) x[tid] = Xk[(size_t)row * CINC + tid];
    else if (tid < 28) x[tid] = temb[t * TEC + (tid - CINC)];
    __syncthreads();
    float acc = bin[tid];
#pragma unroll
    for (int k = 0; k < 28; k++) acc += x[k] * Win[k * HHC + tid];
    float m = blockSum128(acc, s2) * (1.f / 128.f);
    float d = acc - m;
    float v = blockSum128(d * d, s2) * (1.f / 128.f);
    float val = d * rsqrtf(v + EPSLN) * g[tid] + be[tid] + stepemb[(size_t)kidx[b] * HHC + tid];
    h[(size_t)row * HHC + tid] = val;
    hb[(size_t)row * HHC + tid] = f2b(val);
}

__global__ __launch_bounds__(128) void tre_k(const float* __restrict__ temb, const float* __restrict__ Wtr,
                                             const float* __restrict__ btr, float* __restrict__ tre)
{
    int t = blockIdx.x, c = threadIdx.x;
    float acc = btr[c];
#pragma unroll
    for (int k = 0; k < TEC; k++) acc += temb[t * TEC + k] * Wtr[k * HHC + c];
    tre[t * HHC + c] = acc;
}

// ---------------- temporal attention: raw-bf16 LDS staging ----------------

__global__ __launch_bounds__(128) void temporal_attn_k(const unsigned short* __restrict__ qkvb,
                                                       unsigned short* __restrict__ outb)
{
    int bn = blockIdx.x;
    __shared__ unsigned short qkv_s[T1C][408];
    __shared__ float s[NHD][T1C][T1C];
    int tid = threadIdx.x;
    int hh = tid >> 5, lane = tid & 31;
    const unsigned short* base = qkvb + (size_t)bn * T1C * 384;
    for (int cIdx = tid; cIdx < 576; cIdx += 128) {
        uint4 d = *(const uint4*)(base + cIdx * 8);
        int t = cIdx / 48;
        int c0 = (cIdx - t * 48) * 8;
        *(uint4*)(&qkv_s[t][c0]) = d;
    }
    __syncthreads();
    for (int idx = lane; idx < T1C * T1C; idx += 32) {
        int tq = idx / T1C, tk = idx - tq * T1C;
        const unsigned* qp = (const unsigned*)&qkv_s[tq][hh * 32];
        const unsigned* kp = (const unsigned*)&qkv_s[tk][128 + hh * 32];
        float acc = 0.f;
#pragma unroll
        for (int d = 0; d < 16; d++) {
            unsigned a = qp[d], b = kp[d];
            acc += __uint_as_float(a << 16) * __uint_as_float(b << 16);
            acc += __uint_as_float(a & 0xFFFF0000u) * __uint_as_float(b & 0xFFFF0000u);
        }
        s[hh][tq][tk] = acc * SCALEQK;
    }
    __syncthreads();
    if (tid < NHD * T1C) {
        int h2 = tid / T1C, tq = tid - h2 * T1C;
        float mx = -1e30f;
#pragma unroll
        for (int j = 0; j < T1C; j++) mx = fmaxf(mx, s[h2][tq][j]);
        float sum = 0.f;
#pragma unroll
        for (int j = 0; j < T1C; j++) { float ex = expf(s[h2][tq][j] - mx); s[h2][tq][j] = ex; sum += ex; }
        float inv = 1.f / sum;
#pragma unroll
        for (int j = 0; j < T1C; j++) s[h2][tq][j] *= inv;
    }
    __syncthreads();
    int oc = hh * 32 + lane;
#pragma unroll
    for (int t = 0; t < T1C; t++) {
        float acc = 0.f;
#pragma unroll
        for (int tk = 0; tk < T1C; tk++) acc += s[hh][t][tk] * b2f(qkv_s[tk][256 + oc]);
        outb[((size_t)bn * T1C + t) * HHC + oc] = f2b(acc);
    }
}

// ---------------- transpose (+ t_re) ----------------

__global__ __launch_bounds__(256) void addtre_T_k(const float* __restrict__ h, const float* __restrict__ tre,
                                                  float* __restrict__ hBT, unsigned short* __restrict__ hBTb)
{
    int i = blockIdx.x * blockDim.x + threadIdx.x;
    if (i >= MROWS * HHC) return;
    int c = i & (HHC - 1);
    int row = i >> 7;
    int bt = row / NN, n = row - bt * NN;
    int b = bt / T1C, t = bt - b * T1C;
    float v = h[(((size_t)(b * NN + n)) * T1C + t) * HHC + c] + tre[t * HHC + c];
    hBT[i] = v;
    hBTb[i] = f2b(v);
}

// lnT: one wave per row, shfl-only reduction, no barriers
__global__ __launch_bounds__(256) void lnT_k(const float* __restrict__ hBT, const float* __restrict__ g,
                                             const float* __restrict__ be, float* __restrict__ h,
                                             unsigned short* __restrict__ hb)
{
    int row = blockIdx.x * 4 + (threadIdx.x >> 6);
    int lane = threadIdx.x & 63;
    int bt = row / NN, n = row - bt * NN;
    int b = bt / T1C, t = bt - b * T1C;
    const float* rp = hBT + (size_t)row * HHC;
    float x0 = rp[lane], x1 = rp[lane + 64];
    float s = x0 + x1, s2 = x0 * x0 + x1 * x1;
#pragma unroll
    for (int m = 32; m >= 1; m >>= 1) {
        s  += __shfl_xor(s, m, 64);
        s2 += __shfl_xor(s2, m, 64);
    }
    float mu = s * (1.f / 128.f);
    float rstd = rsqrtf(s2 * (1.f / 128.f) - mu * mu + EPSLN);
    float v0 = (x0 - mu) * rstd * g[lane] + be[lane];
    float v1 = (x1 - mu) * rstd * g[lane + 64] + be[lane + 64];
    size_t obase = (((size_t)(b * NN + n)) * T1C + t) * HHC;
    h[obase + lane] = v0;
    h[obase + lane + 64] = v1;
    hb[obase + lane] = f2b(v0);
    hb[obase + lane + 64] = f2b(v1);
}

// ---------------- graph attention ----------------

__global__ __launch_bounds__(256) void emea_k(const float* __restrict__ e, const int* __restrict__ epos,
                                              const float* __restrict__ Wem, const float* __restrict__ bem,
                                              const float* __restrict__ Wea, const float* __restrict__ bea,
                                              float* __restrict__ emp1c, float* __restrict__ eawc)
{
    int r = blockIdx.x * blockDim.x + threadIdx.x;
    if (r >= EEC) return;
    float ev[DEC];
#pragma unroll
    for (int k = 0; k < DEC; k++) ev[k] = e[r * DEC + k];
    int pos = epos[r];
#pragma unroll
    for (int hh = 0; hh < NHD; hh++) {
        float a = bem[hh], b2 = bea[hh];
#pragma unroll
        for (int k = 0; k < DEC; k++) { a += ev[k] * Wem[k * NHD + hh]; b2 += ev[k] * Wea[k * NHD + hh]; }
        emp1c[pos * NHD + hh] = a + 1.f;
        eawc[pos * NHD + hh] = b2;
    }
}

// w = exp(score) in CSR order; 2 edges per iteration for MLP
__global__ __launch_bounds__(128) void score_k(const unsigned short* __restrict__ Q,
                                               const unsigned short* __restrict__ K,
                                               const int* __restrict__ dstCSR, const int* __restrict__ srcCSR,
                                               const float* __restrict__ emp1c, const float* __restrict__ eawc,
                                               float* __restrict__ w)
{
    int bt = blockIdx.y;
    int tid = threadIdx.x;
    int hh = tid & 3, isub = tid >> 2;
    size_t base = (size_t)bt * NN;
    int stride = gridDim.x * 32;
    for (int i = blockIdx.x * 32 + isub; i < EEC; i += 2 * stride) {
        int j = i + stride;
        bool hasj = j < EEC;
        int dn0 = dstCSR[i], sn0 = srcCSR[i];
        int dn1 = hasj ? dstCSR[j] : dn0;
        int sn1 = hasj ? srcCSR[j] : sn0;
        const uint4* q0 = (const uint4*)(Q + (base + dn0) * HHC + hh * 32);
        const uint4* k0 = (const uint4*)(K + (base + sn0) * HHC + hh * 32);
        const uint4* q1 = (const uint4*)(Q + (base + dn1) * HHC + hh * 32);
        const uint4* k1 = (const uint4*)(K + (base + sn1) * HHC + hh * 32);
        float acc0 = 0.f, acc1 = 0.f;
#pragma unroll
        for (int d = 0; d < 4; d++) {
            uint4 a0 = q0[d], b0 = k0[d], a1 = q1[d], b1 = k1[d];
            unsigned av0[4] = {a0.x, a0.y, a0.z, a0.w};
            unsigned bv0[4] = {b0.x, b0.y, b0.z, b0.w};
            unsigned av1[4] = {a1.x, a1.y, a1.z, a1.w};
            unsigned bv1[4] = {b1.x, b1.y, b1.z, b1.w};
#pragma unroll
            for (int jj = 0; jj < 4; jj++) {
                acc0 += __uint_as_float(av0[jj] << 16) * __uint_as_float(bv0[jj] << 16);
                acc0 += __uint_as_float(av0[jj] & 0xFFFF0000u) * __uint_as_float(bv0[jj] & 0xFFFF0000u);
                acc1 += __uint_as_float(av1[jj] << 16) * __uint_as_float(bv1[jj] << 16);
                acc1 += __uint_as_float(av1[jj] & 0xFFFF0000u) * __uint_as_float(bv1[jj] & 0xFFFF0000u);
            }
        }
        float sc0 = acc0 * SCALEQK * emp1c[i * NHD + hh] + eawc[i * NHD + hh];
        w[((size_t)bt * EEC + i) * NHD + hh] = expf(sc0);
        if (hasj) {
            float sc1 = acc1 * SCALEQK * emp1c[j * NHD + hh] + eawc[j * NHD + hh];
            w[((size_t)bt * EEC + j) * NHD + hh] = expf(sc1);
        }
    }
}

// weighted gather-sum over CSR; 8-wide unroll for MLP
__global__ __launch_bounds__(128) void agg_k(const unsigned short* __restrict__ V,
                                             const int* __restrict__ rowptr, const int* __restrict__ srcCSR,
                                             const float* __restrict__ w, unsigned short* __restrict__ outb)
{
    int blk = blockIdx.x;
    int bt = blk / NN, n = blk - bt * NN;
    int tid = threadIdx.x;
    int hh = tid >> 5, lane = tid & 31;
    size_t base = (size_t)bt * NN;
    int oc = hh * 32 + lane;
    const float* wp = w + (size_t)bt * EEC * NHD + hh;
    float den = 0.f, acc = 0.f;
    int s0 = rowptr[n], s1 = rowptr[n + 1];
    int i = s0;
    for (; i + 7 < s1; i += 8) {
        int sn[8];
        float wv[8], vv[8];
#pragma unroll
        for (int u = 0; u < 8; u++) sn[u] = srcCSR[i + u];
#pragma unroll
        for (int u = 0; u < 8; u++) wv[u] = wp[(size_t)(i + u) * NHD];
#pragma unroll
        for (int u = 0; u < 8; u++) vv[u] = b2f(V[(base + sn[u]) * HHC + oc]);
#pragma unroll
        for (int u = 0; u < 8; u++) { acc += wv[u] * vv[u]; den += wv[u]; }
    }
    for (; i + 3 < s1; i += 4) {
        int sn0 = srcCSR[i], sn1 = srcCSR[i + 1], sn2 = srcCSR[i + 2], sn3 = srcCSR[i + 3];
        float w0 = wp[(size_t)i * NHD];
        float w1 = wp[(size_t)(i + 1) * NHD];
        float w2 = wp[(size_t)(i + 2) * NHD];
        float w3 = wp[(size_t)(i + 3) * NHD];
        float v0 = b2f(V[(base + sn0) * HHC + oc]);
        float v1 = b2f(V[(base + sn1) * HHC + oc]);
        float v2 = b2f(V[(base + sn2) * HHC + oc]);
        float v3 = b2f(V[(base + sn3) * HHC + oc]);
        acc += w0 * v0 + w1 * v1 + w2 * v2 + w3 * v3;
        den += (w0 + w1) + (w2 + w3);
    }
    for (; i < s1; i++) {
        int sn = srcCSR[i];
        float wv = wp[(size_t)i * NHD];
        acc += wv * b2f(V[(base + sn) * HHC + oc]);
        den += wv;
    }
    outb[(base + n) * HHC + oc] = f2b(acc / (den + 1e-9f));
}

__global__ __launch_bounds__(128) void hmean_k(const float* __restrict__ hBT, float* __restrict__ hmean)
{
    int n = blockIdx.x, c = threadIdx.x;
    float s = 0.f;
#pragma unroll
    for (int bt = 0; bt < BTC; bt++) s += hBT[((size_t)bt * NN + n) * HHC + c];
    hmean[n * HHC + c] = s * (1.f / BTC);
}

__global__ __launch_bounds__(256) void ein_k(const float* __restrict__ hmean, const int* __restrict__ dst,
                                             const int* __restrict__ src, const float* __restrict__ e,
                                             unsigned short* __restrict__ einb)
{
    int i = blockIdx.x * blockDim.x + threadIdx.x;
    if (i >= EEC * 288) return;
    int r = i / 288, j = i - r * 288;
    float v;
    if (j < HHC) v = hmean[dst[r] * HHC + j];
    else if (j < 2 * HHC) v = hmean[src[r] * HHC + (j - HHC)];
    else if (j < 2 * HHC + DEC) v = e[r * DEC + (j - 2 * HHC)];
    else v = 0.f;
    einb[i] = f2b(v);
}

__global__ __launch_bounds__(256) void eln_k(float* __restrict__ e, const float* __restrict__ emlp,
                                             const float* __restrict__ g, const float* __restrict__ be)
{
    int r = blockIdx.x * blockDim.x + threadIdx.x;
    if (r >= EEC) return;
    float x[DEC];
    float s = 0.f;
#pragma unroll
    for (int c = 0; c < DEC; c++) { x[c] = e[r * DEC + c] + emlp[r * DEC + c]; s += x[c]; }
    float m = s * (1.f / DEC);
    float v = 0.f;
#pragma unroll
    for (int c = 0; c < DEC; c++) { float d = x[c] - m; v += d * d; }
    v *= (1.f / DEC);
    float rstd = rsqrtf(v + EPSLN);
#pragma unroll
    for (int c = 0; c < DEC; c++) e[r * DEC + c] = (x[c] - m) * rstd * g[c] + be[c];
}

// ---------------- output head: one wave per row ----------------

__global__ __launch_bounds__(256) void out_k(const float* __restrict__ h, const float* __restrict__ Wout,
                                             const float* __restrict__ bout, float* __restrict__ out)
{
    int row = blockIdx.x * 4 + (threadIdx.x >> 6);
    int lane = threadIdx.x & 63;
    const float* hp = h + (size_t)row * HHC;
    float x0 = hp[lane], x1 = hp[lane + 64];
    float w00 = Wout[lane * 4 + 0], w01 = Wout[lane * 4 + 1];
    float w02 = Wout[lane * 4 + 2], w03 = Wout[lane * 4 + 3];
    float w10 = Wout[(lane + 64) * 4 + 0], w11 = Wout[(lane + 64) * 4 + 1];
    float w12 = Wout[(lane + 64) * 4 + 2], w13 = Wout[(lane + 64) * 4 + 3];
    float p0 = x0 * w00 + x1 * w10;
    float p1 = x0 * w01 + x1 * w11;
    float p2 = x0 * w02 + x1 * w12;
    float p3 = x0 * w03 + x1 * w13;
#pragma unroll
    for (int m = 32; m >= 1; m >>= 1) {
        p0 += __shfl_xor(p0, m, 64);
        p1 += __shfl_xor(p1, m, 64);
        p2 += __shfl_xor(p2, m, 64);
        p3 += __shfl_xor(p3, m, 64);
    }
    if (lane == 0) {
        float l0 = p0 + bout[0], l1 = p1 + bout[1], l2 = p2 + bout[2], l3 = p3 + bout[3];
        float mx = fmaxf(fmaxf(l0, l1), fmaxf(l2, l3));
        float e0 = expf(l0 - mx), e1 = expf(l1 - mx), e2 = expf(l2 - mx), e3 = expf(l3 - mx);
        float inv = 1.f / (e0 + e1 + e2 + e3);
        float4 o = {e0 * inv, e1 * inv, e2 * inv, e3 * inv};
        *(float4*)(out + (size_t)row * 4) = o;
    }
}

// ---------------- launch ----------------

extern "C" void kernel_launch(void* const* d_in, const int* in_sizes, int n_in,
                              void* d_out, int out_size, void* d_ws, size_t ws_size,
                              hipStream_t stream)
{
    const float* Xk      = (const float*)d_in[0];
    const float* temb    = (const float*)d_in[1];
    const float* stepemb = (const float*)d_in[2];
    const float* Wtr     = (const float*)d_in[3];
    const float* btr     = (const float*)d_in[4];
    const float* Win     = (const float*)d_in[5];
    const float* bin     = (const float*)d_in[6];
    const float* gin     = (const float*)d_in[7];
    const float* bein    = (const float*)d_in[8];
    const float* We      = (const float*)d_in[9];
    const float* bE      = (const float*)d_in[10];
    const float* aw      = (const float*)d_in[11];
    const float* ab      = (const float*)d_in[12];
    const float* ow      = (const float*)d_in[13];
    const float* ob      = (const float*)d_in[14];
    const float* tng     = (const float*)d_in[15];
    const float* tnb     = (const float*)d_in[16];
    const float* f1w     = (const float*)d_in[17];
    const float* f1b     = (const float*)d_in[18];
    const float* f2w     = (const float*)d_in[19];
    const float* f2b_    = (const float*)d_in[20];
    const float* fng     = (const float*)d_in[21];
    const float* fnb     = (const float*)d_in[22];
    const float* Wq      = (const float*)d_in[23];
    const float* Wk      = (const float*)d_in[24];
    const float* Wv      = (const float*)d_in[25];
    const float* Wo      = (const float*)d_in[26];
    const float* bo      = (const float*)d_in[27];
    const float* Wem     = (const float*)d_in[28];
    const float* bem     = (const float*)d_in[29];
    const float* Wea     = (const float*)d_in[30];
    const float* bea     = (const float*)d_in[31];
    const float* e1w     = (const float*)d_in[32];
    const float* e1b     = (const float*)d_in[33];
    const float* e2w     = (const float*)d_in[34];
    const float* e2b     = (const float*)d_in[35];
    const float* gng     = (const float*)d_in[36];
    const float* gnb     = (const float*)d_in[37];
    const float* eng     = (const float*)d_in[38];
    const float* enb     = (const float*)d_in[39];
    const float* Wout    = (const float*)d_in[40];
    const float* bout    = (const float*)d_in[41];
    const int*   kidx    = (const int*)d_in[42];
    const int*   eidx    = (const int*)d_in[43];
    float* outp = (float*)d_out;

    char* wsp = (char*)d_ws;
    auto alloc = [&](size_t nbytes) -> void* {
        void* p = (void*)wsp;
        wsp += (nbytes + 255) & ~(size_t)255;
        return p;
    };
    float* h     = (float*)alloc((size_t)MROWS * HHC * 4);
    unsigned short* hb = (unsigned short*)alloc((size_t)MROWS * HHC * 2);
    float* hBT   = (float*)alloc((size_t)MROWS * HHC * 4);
    unsigned short* hBTb = (unsigned short*)alloc((size_t)MROWS * HHC * 2);
    float* bufC  = (float*)alloc((size_t)MROWS * 384 * 4);
    unsigned short* bufDb = (unsigned short*)alloc((size_t)MROWS * HHC * 2);
    float* ebuf  = (float*)alloc((size_t)EEC * DEC * 4);
    float* emp1c = (float*)alloc((size_t)EEC * NHD * 4);
    float* eawc  = (float*)alloc((size_t)EEC * NHD * 4);
    float* emid  = (float*)alloc((size_t)EEC * 64 * 4);
    float* emlp  = (float*)alloc((size_t)EEC * DEC * 4);
    float* hmean = (float*)alloc((size_t)NN * HHC * 4);
    float* tre   = (float*)alloc((size_t)T1C * HHC * 4);
    float* wbuf  = (float*)alloc((size_t)BTC * EEC * NHD * 4);
    float* degmaxf = (float*)alloc(4);
    int* degi   = (int*)alloc((size_t)NN * 4);
    int* dst    = (int*)alloc((size_t)EEC * 4);
    int* srcA   = (int*)alloc((size_t)EEC * 4);
    int* srcCSR = (int*)alloc((size_t)EEC * 4);
    int* dstCSR = (int*)alloc((size_t)EEC * 4);
    int* epos   = (int*)alloc((size_t)EEC * 4);
    int* rowptr = (int*)alloc((size_t)(NN + 1) * 4);
    int* cursor = (int*)alloc((size_t)NN * 4);
    unsigned short* awP   = (unsigned short*)alloc((size_t)LLC * 384 * 128 * 2);
    unsigned short* owP   = (unsigned short*)alloc((size_t)LLC * 128 * 128 * 2);
    unsigned short* f1P   = (unsigned short*)alloc((size_t)LLC * 256 * 128 * 2);
    unsigned short* f2P   = (unsigned short*)alloc((size_t)LLC * 128 * 256 * 2);
    unsigned short* WqkvP = (unsigned short*)alloc((size_t)LLC * 384 * 128 * 2);
    unsigned short* WoP   = (unsigned short*)alloc((size_t)LLC * 128 * 128 * 2);
    unsigned short* e1T   = (unsigned short*)alloc((size_t)LLC * 64 * 288 * 2);

    unsigned short* bufCb = (unsigned short*)bufC;
    unsigned short* midb  = (unsigned short*)bufC;
    unsigned short* Qc    = (unsigned short*)bufC;
    unsigned short* Kc    = Qc + (size_t)MROWS * HHC;
    unsigned short* Vc    = Kc + (size_t)MROWS * HHC;
    unsigned short* einb  = (unsigned short*)bufC;

    {
        auto cwp = [&](const float* W, unsigned short* Bp, int K, int N, int noff, int Ntot) {
            int total = LLC * K * N;
            convwp_k<<<(total + 255) / 256, 256, 0, stream>>>(W, Bp, LLC, K, N, noff, Ntot);
        };
        cwp(aw,  awP, 128, 384, 0, 384);
        cwp(ow,  owP, 128, 128, 0, 128);
        cwp(f1w, f1P, 128, 256, 0, 256);
        cwp(f2w, f2P, 256, 128, 0, 128);
        cwp(Wq,  WqkvP, 128, 128, 0,   384);
        cwp(Wk,  WqkvP, 128, 128, 128, 384);
        cwp(Wv,  WqkvP, 128, 128, 256, 384);
        cwp(Wo,  WoP, 128, 128, 0, 128);
        int totalE1 = LLC * 64 * 288;
        convw_k<<<(totalE1 + 255) / 256, 256, 0, stream>>>(e1w, e1T, LLC, 272, 64, 288, 64 * 288, 0);
    }

    zero_deg_k<<<(NN + 255) / 256, 256, 0, stream>>>(degi);
    build_edges_k<<<(EEC + 255) / 256, 256, 0, stream>>>(eidx, dst, srcA, degi);
    scan_k<<<1, 256, 0, stream>>>(degi, rowptr, cursor, degmaxf);
    feat_k<<<(EEC + 255) / 256, 256, 0, stream>>>(dst, srcA, degi, degmaxf, cursor, srcCSR, dstCSR, epos, We, bE, ebuf);

    embed_k<<<MROWS, 128, 0, stream>>>(Xk, temb, Win, bin, gin, bein, stepemb, kidx, h, hb);
    tre_k<<<T1C, 128, 0, stream>>>(temb, Wtr, btr, tre);

    for (int l = 0; l < LLC; l++) {
        const unsigned short* awP_l   = awP   + (size_t)l * 384 * 128;
        const unsigned short* owP_l   = owP   + (size_t)l * 128 * 128;
        const unsigned short* f1P_l   = f1P   + (size_t)l * 256 * 128;
        const unsigned short* f2P_l   = f2P   + (size_t)l * 128 * 256;
        const unsigned short* WqkvP_l = WqkvP + (size_t)l * 384 * 128;
        const unsigned short* WoP_l   = WoP   + (size_t)l * 128 * 128;
        const unsigned short* e1T_l   = e1T   + (size_t)l * 64 * 288;
        const float* ab_l  = ab  + (size_t)l * 3 * HHC;
        const float* ob_l  = ob  + (size_t)l * HHC;
        const float* tng_l = tng + (size_t)l * HHC;
        const float* tnb_l = tnb + (size_t)l * HHC;
        const float* f1b_l = f1b + (size_t)l * 256;
        const float* f2b_l = f2b_ + (size_t)l * HHC;
        const float* fng_l = fng + (size_t)l * HHC;
        const float* fnb_l = fnb + (size_t)l * HHC;
        const float* bo_l  = bo  + (size_t)l * HHC;
        const float* Wem_l = Wem + (size_t)l * DEC * NHD;
        const float* bem_l = bem + (size_t)l * NHD;
        const float* Wea_l = Wea + (size_t)l * DEC * NHD;
        const float* bea_l = bea + (size_t)l * NHD;
        const float* e1b_l = e1b + (size_t)l * 64;
        const float* e2w_l = e2w + (size_t)l * 64 * DEC;
        const float* e2b_l = e2b + (size_t)l * DEC;
        const float* gng_l = gng + (size_t)l * HHC;
        const float* gnb_l = gnb + (size_t)l * HHC;
        const float* eng_l = eng + (size_t)l * DEC;
        const float* enb_l = enb + (size_t)l * DEC;

        // temporal attention (qkv in bf16)
        run_gemm2<128, 0, 2>(hb, awP_l, ab_l, nullptr, bufCb, nullptr, nullptr, nullptr, MROWS, 384, stream);
        temporal_attn_k<<<BBC * NN, 128, 0, stream>>>(bufCb, bufDb);
        run_gemm2<128, 3, 3>(bufDb, owP_l, ob_l, h, hb, h, tng_l, tnb_l, MROWS, 128, stream);
        // FFN
        run_gemm2<128, 1, 2>(hb, f1P_l, f1b_l, nullptr, midb, nullptr, nullptr, nullptr, MROWS, 256, stream);
        run_gemm2<256, 3, 1>(midb, f2P_l, f2b_l, h, nullptr, h, fng_l, fnb_l, MROWS, 128, stream);
        // + t_re, transpose to [BT, N, H]
        addtre_T_k<<<(MROWS * HHC + 255) / 256, 256, 0, stream>>>(h, tre, hBT, hBTb);
        // graph attention: fused QKV GEMM, split compact outputs
        run_gemm2<128, 0, 4>(hBTb, WqkvP_l, nullptr, nullptr, Qc, nullptr, nullptr, nullptr, MROWS, 384, stream);
        emea_k<<<(EEC + 255) / 256, 256, 0, stream>>>(ebuf, epos, Wem_l, bem_l, Wea_l, bea_l, emp1c, eawc);
        score_k<<<dim3(64, BTC), 128, 0, stream>>>(Qc, Kc, dstCSR, srcCSR, emp1c, eawc, wbuf);
        agg_k<<<BTC * NN, 128, 0, stream>>>(Vc, rowptr, srcCSR, wbuf, bufDb);
        run_gemm2<128, 2, 1>(bufDb, WoP_l, bo_l, hBT, nullptr, hBT, nullptr, nullptr, MROWS, 128, stream);
        // edge update
        hmean_k<<<NN, 128, 0, stream>>>(hBT, hmean);
        ein_k<<<(EEC * 288 + 255) / 256, 256, 0, stream>>>(hmean, dst, srcA, ebuf, einb);
        gemm_mfma_k<2, 1, 1><<<(EEC + 31) / 32, 256, 0, stream>>>(einb, e1T_l, e1b_l, emid, nullptr,
                                                                  nullptr, nullptr, nullptr, EEC, 288);
        gemm_k<0, 64><<<(EEC + 15) / 16, 128, 0, stream>>>(emid, e2w_l, e2b_l, emlp, EEC, DEC);
        eln_k<<<(EEC + 255) / 256, 256, 0, stream>>>(ebuf, emlp, eng_l, enb_l);
        // final LN + transpose back to [B,N,T1,H] (wave-per-row)
        lnT_k<<<MROWS / 4, 256, 0, stream>>>(hBT, gng_l, gnb_l, h, hb);
    }

    out_k<<<MROWS / 4, 256, 0, stream>>>(h, Wout, bout, outp);
}